// Round 5
// baseline (541.339 us; speedup 1.0000x reference)
//
#include <hip/hip_runtime.h>

// Problem: B=2, S=2304, C=1280, NH=8, DH=160, MH=64, SR=48, BH=16
// R11: 517us (attn 2x131). Single-K/V rotated pipeline, 3 blocks/CU. VALU is
//      now the top pipe (38.6%) at 2.2x MfmaUtil; per-iter wall 8.7K cyc vs
//      1.7K cyc MFMA demand. Staging+softmax overhead per key is the wall.
// R12: (a) 8-wave / 128-query blocks: K+V DMA + barriers amortized over 2x
//      MFMA; per-bh K/V refetch halves (18 blocks/bh not 36). LDS 60KB ->
//      2 blocks/CU, grid 288 all-resident. (b) T13 defer-rescale (THR=8):
//      skip o-rescale + max update when tile max <= mrun+8 (wave-uniform
//      __all); exact in f32. PV no longer gated by the DPP-max/alpha chain.
//      (c) Ps writes issued right after exp, before the row-sum reduce.

typedef unsigned short u16;
typedef unsigned int   u32;
typedef unsigned char  u8;
typedef __attribute__((ext_vector_type(8))) short bf16x8;   // 8 bf16 = 4 VGPRs
typedef __attribute__((ext_vector_type(4))) float f32x4;

#define MFMA16(a,b,c) __builtin_amdgcn_mfma_f32_16x16x32_bf16((a),(b),(c),0,0,0)
#define INVS 0.07905694150420949f                 // 1/sqrt(160)
#define KPAD 168                                  // K row stride (u16): 84 dw -> b128 reads at bank floor
#define PSTR 76                                   // Ps row stride (u16): 38 dw -> write quads on distinct banks

typedef const __attribute__((address_space(1))) void gvoid;
typedef __attribute__((address_space(3))) void lvoid;
#define GLD16(gp, lp) __builtin_amdgcn_global_load_lds((gvoid*)(gp), (lvoid*)(lp), 16, 0, 0)

__device__ __forceinline__ u16 f2b(float f) {            // fp32 -> bf16 RNE
  u32 u = __float_as_uint(f);
  return (u16)((u + 0x7fffu + ((u >> 16) & 1u)) >> 16);
}
__device__ __forceinline__ float b2f(u16 v) { return __uint_as_float(((u32)v) << 16); }

// DPP reduction over a 16-lane row (exactly our l16 domain = one DPP row):
// quad_perm(1,0,3,2)=0xB1, quad_perm(2,3,0,1)=0x4E, row_half_mirror=0x141, row_mirror=0x140
#define DPPF(x, ctrl) __int_as_float(__builtin_amdgcn_update_dpp(0, __float_as_int(x), (ctrl), 0xf, 0xf, true))
__device__ __forceinline__ float row_max16(float x) {
  x = fmaxf(x, DPPF(x, 0xB1));
  x = fmaxf(x, DPPF(x, 0x4E));
  x = fmaxf(x, DPPF(x, 0x141));
  x = fmaxf(x, DPPF(x, 0x140));
  return x;
}
__device__ __forceinline__ float row_sum16(float x) {
  x += DPPF(x, 0xB1);
  x += DPPF(x, 0x4E);
  x += DPPF(x, 0x141);
  x += DPPF(x, 0x140);
  return x;
}

// ---------------- mask-mode detector: 0=i32, 1=u8, 2=bf16, 3=f32 ----------------
__global__ __launch_bounds__(256) void maskdet(const u32* __restrict__ mid, u32* mode)
{
  __shared__ int a0, a1, a2, a3;
  int tid = threadIdx.x;
  if (tid == 0) { a0 = 1; a1 = 1; a2 = 1; a3 = 0; }
  __syncthreads();
  #pragma unroll
  for (int j = 0; j < 4; j++) {
    u32 w = mid[tid*4 + j];                      // first 4 KiB, in-bounds for all dtypes
    if (w > 1u)                      atomicAnd(&a0, 0);  // not i32 bools
    if (w & 0xFEFEFEFEu)             atomicAnd(&a1, 0);  // not u8 bools
    if (w != 0u && w != 0x3F800000u) atomicAnd(&a2, 0);  // not f32 {0,1}
    if ((w & 0xFFFFu) == 0x3F80u)    atomicOr(&a3, 1);   // bf16 1.0 in low half
  }
  __syncthreads();
  if (tid == 0) mode[0] = a0 ? 0u : (a1 ? 1u : (a3 ? 2u : (a2 ? 3u : 0u)));
}

// ---------------- nearest-downsample masks 64x64 -> 48x48 flattened to S ----------------
__global__ void maskprep(const void* mid, const float* __restrict__ mig_in,
                         float* __restrict__ mk, float* __restrict__ mg, const u32* mode)
{
  int j = blockIdx.x*256 + threadIdx.x;
  if (j >= 2*2304) return;
  u32 md = mode[0];
  int b = j / 2304, s = j % 2304;
  int i = s / 48, jj = s % 48;
  int ih = (i*4)/3, iw = (jj*4)/3;        // arange(48)*64//48
  int src = b*4096 + ih*64 + iw;
  bool on;
  if      (md == 0) on = ((const int*)mid)[src] != 0;
  else if (md == 1) on = ((const u8*)mid)[src]  != 0;
  else if (md == 2) on = ((const u16*)mid)[src] != 0;
  else              on = ((const float*)mid)[src] != 0.0f;
  mk[j] = on ? 1.0f : 0.0f;
  mg[j] = mig_in[src];                     // mask_ig is fp32
}

// ---------------- transpose weights: fp32 W[k][n] -> bf16 WT[n][k], 4 matrices --------------
__global__ __launch_bounds__(256) void transpose_w(
    const float* __restrict__ W0, const float* __restrict__ W1,
    const float* __restrict__ W2, const float* __restrict__ W3, u16* __restrict__ WT)
{
  __shared__ u16 t[32][33];
  int z = blockIdx.z;
  const float* s = (z==0)?W0:(z==1)?W1:(z==2)?W2:W3;
  u16* d = WT + (size_t)z*1280*1280;
  int tx = threadIdx.x & 31, ty = (threadIdx.x >> 5) * 4;
  int x = blockIdx.x*32 + tx;          // src col (n)
  int y = blockIdx.y*32 + ty;          // src row (k)
  #pragma unroll
  for (int i=0;i<4;i++) t[ty+i][tx] = f2b(s[(size_t)(y+i)*1280 + x]);
  __syncthreads();
  int x2 = blockIdx.y*32 + tx, y2 = blockIdx.x*32 + ty;
  #pragma unroll
  for (int i=0;i<4;i++) d[(size_t)(y2+i)*1280 + x2] = t[tx][ty+i];   // WT[n][k] = W[k][n]
}

// ---------------- convert fp32 -> bf16 (unpadded) ----------------
__global__ __launch_bounds__(256) void conv(const float* __restrict__ src, u16* __restrict__ dst, int n)
{
  for (int i = blockIdx.x*256 + threadIdx.x; i < n; i += gridDim.x*256)
    dst[i] = f2b(src[i]);
}

// ---------------- convert store_ks fp32 [bh][s][160] -> padded bf16 [bh][s][168] ------------
__global__ __launch_bounds__(256) void convK(const float* __restrict__ src, u16* __restrict__ dst)
{
  const int n = 16*2304*KPAD;
  for (int i = blockIdx.x*256 + threadIdx.x; i < n; i += gridDim.x*256) {
    int row = i / KPAD, col = i % KPAD;
    dst[i] = (col < 160) ? f2b(src[(size_t)row*160 + col]) : (u16)0;
  }
}

// ---------------- transpose store_vs fp32 [16][2304][160] -> bf16 vst[16][160][2304] ---------
__global__ __launch_bounds__(256) void transpose_vs(const float* __restrict__ src, u16* __restrict__ dst)
{
  __shared__ u16 t[32][33];
  int z = blockIdx.z;
  u16* d = dst + (size_t)z*160*2304;
  int tx = threadIdx.x & 31, ty = (threadIdx.x >> 5) * 4;
  int r0 = blockIdx.x*32, c0 = blockIdx.y*32;
  #pragma unroll
  for (int i=0;i<4;i++)
    t[ty+i][tx] = f2b(src[((size_t)z*2304 + r0+ty+i)*160 + c0+tx]);
  __syncthreads();
  #pragma unroll
  for (int i=0;i<4;i++) d[(size_t)(c0+ty+i)*2304 + r0+tx] = t[tx][ty+i]; // d[c][r] = s[r][c]
}

// ---------------- GEMM: 128x128 tile, BK=32, 4 waves (2x2), 16x16x32 MFMA ----------------
// kind 0: A=hidB, BT=WT[z]; z=0->q*INVS [bh][s][160], z=1->k PADDED [bh][s][168], z=2->v^T [bh][d][s]
// kind 1: A=comb, BT=WoT;   out = A@Wo + bias -> fp32 d_out
__global__ __launch_bounds__(256, 2) void gemm128(
    const u16* __restrict__ A, const u16* __restrict__ BT,
    u16* __restrict__ dq, u16* __restrict__ dk, u16* __restrict__ dvt,
    float* __restrict__ dout, const float* __restrict__ bias, int kind)
{
  __shared__ __align__(16) u16 As[128*40];   // pad 32->40: 80B stride breaks conflicts
  __shared__ __align__(16) u16 Bs[128*40];
  int tid = threadIdx.x;
  int m0 = blockIdx.x*128, n0 = blockIdx.y*128;
  int z = blockIdx.z;
  const u16* Bt = BT + (size_t)z*1280*1280;
  int w = tid>>6, lane = tid&63, quad = lane>>4, l16 = lane&15;
  int wm = w&1, wn = w>>1;
  int arow = tid>>1, acg = (tid&1)*16;
  f32x4 zero = {0.f,0.f,0.f,0.f};
  f32x4 acc[4][4];
  #pragma unroll
  for (int a=0;a<4;a++) { acc[a][0]=zero; acc[a][1]=zero; acc[a][2]=zero; acc[a][3]=zero; }
  const u16* ga = A  + (size_t)(m0+arow)*1280 + acg;
  const u16* gb = Bt + (size_t)(n0+arow)*1280 + acg;
  for (int k0 = 0; k0 < 1280; k0 += 32) {
    uint4 a0 = *(const uint4*)(ga + k0);
    uint4 a1 = *(const uint4*)(ga + k0 + 8);
    uint4 b0 = *(const uint4*)(gb + k0);
    uint4 b1 = *(const uint4*)(gb + k0 + 8);
    __syncthreads();
    *(uint4*)&As[arow*40 + acg]     = a0;
    *(uint4*)&As[arow*40 + acg + 8] = a1;
    *(uint4*)&Bs[arow*40 + acg]     = b0;
    *(uint4*)&Bs[arow*40 + acg + 8] = b1;
    __syncthreads();
    bf16x8 af[4], bfr[4];
    #pragma unroll
    for (int mt=0; mt<4; mt++) af[mt]  = *(const bf16x8*)&As[(wm*64+mt*16+l16)*40 + quad*8];
    #pragma unroll
    for (int nt=0; nt<4; nt++) bfr[nt] = *(const bf16x8*)&Bs[(wn*64+nt*16+l16)*40 + quad*8];
    #pragma unroll
    for (int mt=0; mt<4; mt++)
      #pragma unroll
      for (int nt=0; nt<4; nt++)
        acc[mt][nt] = MFMA16(af[mt], bfr[nt], acc[mt][nt]);
  }
  #pragma unroll
  for (int mt=0; mt<4; mt++) {
    int r0g = m0 + wm*64 + mt*16 + quad*4;          // 4 consecutive rows (reg 0..3)
    #pragma unroll
    for (int nt=0; nt<4; nt++) {
      int col = n0 + wn*64 + nt*16 + l16;
      if (kind == 1) {
        float bi = bias[col];
        #pragma unroll
        for (int r=0;r<4;r++) dout[(size_t)(r0g+r)*1280 + col] = acc[mt][nt][r] + bi;
      } else {
        int h = col/160, d = col%160;
        if (z == 2) {                               // v -> [bh][d][s], s consecutive
          int b = r0g/2304, s0 = r0g%2304;
          size_t base = ((size_t)((b*8+h)*160 + d))*2304 + s0;
          ushort4 pk;
          pk.x = f2b(acc[mt][nt][0]); pk.y = f2b(acc[mt][nt][1]);
          pk.z = f2b(acc[mt][nt][2]); pk.w = f2b(acc[mt][nt][3]);
          *(ushort4*)&dvt[base] = pk;
        } else {
          #pragma unroll
          for (int r=0;r<4;r++) {
            int rg = r0g + r;
            int b = rg/2304, s = rg%2304;
            if (z == 0) dq[((size_t)(b*8+h)*2304 + s)*160  + d] = f2b(acc[mt][nt][r] * INVS);
            else        dk[((size_t)(b*8+h)*2304 + s)*KPAD + d] = f2b(acc[mt][nt][r]);
          }
        }
      }
    }
  }
}

// ---------------- Attention (flash-style, online softmax), 8 waves / 128 queries. -----------
// ip=0: self -> hs (bf16). ip=1: keys=sksP, V=vst, per-key mask, combine -> comb bf16.
// SINGLE-buffered K and V, rotated pipeline:
//   QK^T(kc) | barA (Ks consumed, V(kc) drained) | issue K(kc+1)
//   softmax(T13 defer)+Ps+PV(kc) (covers K DMA) | barB | issue V(kc+1).
// LDS 60KB -> 2 blocks/CU; grid 288 all-resident. K/V staged once per 128 queries.
__global__ __launch_bounds__(512, 4) void attn(
    const u16* __restrict__ qg,   // [16][2304][160], pre-scaled by INVS
    const u16* __restrict__ kg,   // PADDED [16][2304][168]
    const u16* __restrict__ vtg,  // [16][160][2304]
    const float* __restrict__ maskkey, const float* __restrict__ mig,
    u16* __restrict__ hs, u16* __restrict__ comb,
    const void* scaleptr, int ip)
{
  __shared__ __align__(16) u16 Ks[64*KPAD];     // 21504 B single buffer
  __shared__ __align__(16) u16 Vs[160*64];      // 20480 B, XOR-swizzled granules
  __shared__ __align__(16) u16 Ps[8*16*PSTR];   // 19456 B per-wave P relayout
  // XCD-aware remap: 288 blocks, 36 per XCD = 2 bh x 18 q-tiles. XCD c owns
  // bh {2c, 2c+1} -> K+V working set ~1.5MB per bh fits 4MB L2.
  int id = blockIdx.y*18 + blockIdx.x;
  int xc = id & 7, kq = id >> 3;                 // kq in 0..35
  int bh = 2*xc + (kq >= 18 ? 1 : 0);
  int qt = (kq >= 18) ? kq - 18 : kq;
  int tid = threadIdx.x, w = tid>>6, lane = tid&63, quad = lane>>4, l16 = lane&15;
  int q0 = qt*128 + w*16;                        // wave's 16 queries

  const char* kgbytes = (const char*)kg;
  const char* ktile0 = kgbytes + ((size_t)bh*2304)*(KPAD*2);
  const char* vbytes = (const char*)vtg + ((size_t)bh*160)*2304*2;  // V^T slice base

  // V DMA lane geometry (512 threads): granule idx = tid + round*512;
  // d-row = idx>>3 (rounds add 64/128 -> row&7 invariant), slot = tid&7.
  // Lane fetches source granule slot^(row&7); LDS image then has granule g of
  // row d at byte d*128 + (g^(d&7))*16 (conflict-free b128 reads, no pad).
  int vrow = tid>>3, vslot = tid&7;
  int vsw  = ((vslot ^ (vrow & 7)) << 4);        // swizzled source byte offset

  // ---- prologue: issue K(0) + V(0) DMA (both drained by the pre-loop barrier) ----
  {
    int off = tid*16;
    GLD16(ktile0 + off,         (char*)Ks + off);
    GLD16(ktile0 + 8192 + off,  (char*)Ks + 8192 + off);
    if (tid < 320) GLD16(ktile0 + 16384 + off, (char*)Ks + 16384 + off);
    GLD16(vbytes + (size_t)vrow*4608 + vsw,          (char*)Vs + tid*16);
    GLD16(vbytes + (size_t)(vrow+64)*4608 + vsw,     (char*)Vs + tid*16 + 8192);
    if (tid < 256) GLD16(vbytes + (size_t)(vrow+128)*4608 + vsw, (char*)Vs + tid*16 + 16384);
  }

  bf16x8 aq[5];                                // Q frags: A[m=l16][k=quad*8+j], 5 ksteps
  {
    const u16* qrow = qg + ((size_t)bh*2304 + q0 + l16)*160 + quad*8;
    #pragma unroll
    for (int ks=0; ks<5; ks++) aq[ks] = *(const bf16x8*)(qrow + ks*32);
  }
  f32x4 zero = {0.f,0.f,0.f,0.f};
  f32x4 o[10];
  #pragma unroll
  for (int i=0;i<10;i++) o[i] = zero;
  float mrun[4] = {-1e30f,-1e30f,-1e30f,-1e30f};
  float lrun[4] = {0.f,0.f,0.f,0.f};

  const float* mkb = ip ? (maskkey + (bh & 1)*2304) : nullptr;
  float mcur[4] = {1.f,1.f,1.f,1.f};
  if (ip) {
    #pragma unroll
    for (int nt=0;nt<4;nt++) mcur[nt] = mkb[nt*16 + l16];
  }

  __syncthreads();                             // drains K(0)+V(0)+Q loads

  for (int kc = 0; kc < 36; kc++) {
    // ---- prefetch next iteration's mask values (off the score critical path) ----
    float mnxt[4] = {1.f,1.f,1.f,1.f};
    if (ip && kc < 35) {
      #pragma unroll
      for (int nt=0;nt<4;nt++) mnxt[nt] = mkb[(kc+1)*64 + nt*16 + l16];
    }

    // ---- scores S[16 q][64 keys] = Q K^T (Q pre-scaled), K from LDS ----
    f32x4 sc[4];
    bool keep[4];
    #pragma unroll
    for (int nt=0; nt<4; nt++) {
      f32x4 s = zero;
      #pragma unroll
      for (int ks=0; ks<5; ks++) {
        bf16x8 bk = *(const bf16x8*)&Ks[(nt*16+l16)*KPAD + ks*32 + quad*8];
        s = MFMA16(aq[ks], bk, s);
      }
      keep[nt] = true;
      if (ip && mcur[nt] == 0.0f) {
        keep[nt] = false;
        #pragma unroll
        for (int r=0;r<4;r++) s[r] = -1e30f;
      }
      sc[nt] = s;
    }

    __syncthreads();                           // barA: Ks consumed by all waves

    // ---- issue K(kc+1) DMA into the (now free) single K buffer; drains at barB ----
    if (kc < 35) {
      const char* tile = ktile0 + (size_t)(kc+1)*64*(KPAD*2);
      int off = tid*16;
      GLD16(tile + off,        (char*)Ks + off);
      GLD16(tile + 8192 + off, (char*)Ks + 8192 + off);
      if (tid < 320) GLD16(tile + 16384 + off, (char*)Ks + 16384 + off);
    }

    // ---- T13 defer-rescale softmax (row = quad*4+r). Check max growth; only
    //      rescale when some row's tile-max exceeds mrun+8 (rare). Exact in f32.
    float mrow[4];
    #pragma unroll
    for (int r=0;r<4;r++) {
      float mr = fmaxf(fmaxf(sc[0][r], sc[1][r]), fmaxf(sc[2][r], sc[3][r]));
      mrow[r] = row_max16(mr);
    }
    bool fastok = (mrow[0] <= mrun[0]+8.f) & (mrow[1] <= mrun[1]+8.f)
                & (mrow[2] <= mrun[2]+8.f) & (mrow[3] <= mrun[3]+8.f);
    if (!__all(fastok)) {                      // slow path: grow max, rescale o/l
      #pragma unroll
      for (int r=0;r<4;r++) {
        float nm = fmaxf(mrun[r], mrow[r]);
        float alpha = __expf(fminf(mrun[r] - nm, 0.f));
        mrun[r] = nm;
        lrun[r] *= alpha;
        #pragma unroll
        for (int nt2=0; nt2<10; nt2++) o[nt2][r] *= alpha;
      }
    }
    // p = exp(sc - mrun) (bounded by e^8); write Ps immediately (PV operand)
    float p[4][4];
    #pragma unroll
    for (int nt=0;nt<4;nt++)
      #pragma unroll
      for (int r=0;r<4;r++) {
        float e = keep[nt] ? __expf(sc[nt][r] - mrun[r]) : 0.f;
        p[nt][r] = e;
        Ps[(w*16 + quad*4 + r)*PSTR + nt*16 + l16] = f2b(e);
      }
    #pragma unroll
    for (int r=0;r<4;r++) {
      float rs = (p[0][r]+p[1][r]) + (p[2][r]+p[3][r]);
      rs = row_sum16(rs);
      lrun[r] += rs;
    }

    // ---- O += P V, V B-frags from LDS (XOR-swizzled, bank-floor b128 reads) ----
    #pragma unroll
    for (int kb=0; kb<2; kb++) {
      bf16x8 ap = *(const bf16x8*)&Ps[(w*16 + l16)*PSTR + kb*32 + quad*8];
      #pragma unroll
      for (int nt=0; nt<10; nt++) {
        int d = nt*16 + l16;
        bf16x8 bv = *(const bf16x8*)((const char*)Vs + d*128 + (((kb*4 + quad) ^ (l16 & 7)) << 4));
        o[nt] = MFMA16(ap, bv, o[nt]);
      }
    }

    if (ip) {
      #pragma unroll
      for (int nt=0;nt<4;nt++) mcur[nt] = mnxt[nt];
    }

    __syncthreads();                           // barB: K(kc+1) drained; Vs consumed by all

    // ---- issue V(kc+1) DMA (drains at next iter's barA, covered by QK^T) ----
    if (kc < 35) {
      const char* vsrc = vbytes + (size_t)(kc+1)*128;   // key-col offset (kc+1)*64 keys *2B
      GLD16(vsrc + (size_t)vrow*4608 + vsw,          (char*)Vs + tid*16);
      GLD16(vsrc + (size_t)(vrow+64)*4608 + vsw,     (char*)Vs + tid*16 + 8192);
      if (tid < 256) GLD16(vsrc + (size_t)(vrow+128)*4608 + vsw, (char*)Vs + tid*16 + 16384);
    }
  }

  // ---- epilogue ----
  int b = bh>>3, h = bh&7;
  float scl = 0.f;
  if (ip) {                                   // scalar dtype self-detect (0.5 decodes both ways)
    u16 v0 = ((const u16*)scaleptr)[0];
    int e = (v0 >> 7) & 0xFF;
    scl = (v0 != 0 && e >= 100 && e <= 133) ? b2f(v0) : ((const float*)scaleptr)[0];
  }
  #pragma unroll
  for (int r=0;r<4;r++) {
    int s = q0 + quad*4 + r;
    float linv = (lrun[r] > 0.f) ? 1.0f/lrun[r] : 0.f;
    size_t base = ((size_t)b*2304 + s)*1280 + h*160;
    if (!ip) {
      #pragma unroll
      for (int nt=0;nt<10;nt++) hs[base + nt*16 + l16] = f2b(o[nt][r]*linv);
    } else {
      float f = mig[b*2304 + s]*scl*linv;    // mig uses TRUE b
      #pragma unroll
      for (int nt=0;nt<10;nt++)
        comb[base + nt*16 + l16] = f2b(b2f(hs[base + nt*16 + l16]) + o[nt][r]*f);
    }
  }
}

// ---------------- launch ----------------
extern "C" void kernel_launch(void* const* d_in, const int* in_sizes, int n_in,
                              void* d_out, int out_size, void* d_ws, size_t ws_size,
                              hipStream_t stream)
{
  const float* hid = (const float*)d_in[0];
  const float* Wq  = (const float*)d_in[1];
  const float* Wk  = (const float*)d_in[2];
  const float* Wv  = (const float*)d_in[3];
  const float* Wo  = (const float*)d_in[4];
  const float* bo  = (const float*)d_in[5];
  const float* sks = (const float*)d_in[6];
  const float* svs = (const float*)d_in[7];
  const void*  mid = d_in[8];
  const float* mig = (const float*)d_in[9];
  const void*  scl = d_in[10];

  char* ws = (char*)d_ws;                    // 69.9 MiB total (aliased, stream-ordered)
  float* mk   = (float*)(ws);                // [2][2304]              18432 B
  float* mg   = (float*)(ws + 18432);        // [2][2304]              18432 B
  u32*  mode  = (u32*)(ws + 36864);          // 256 B
  u16*  WT    = (u16*)(ws + 40960);          // 4 x 1280x1280 bf16  13107200 B
  u16*  slotA = (u16*)(ws + 13148160);       // hidB unpadded; later sksP padded  12386304
  u16*  q     = (u16*)(ws + 25534464);       // [16][2304][160] (pre-scaled)      11796480
  u16*  slotB = (u16*)(ws + 37330944);       // kP padded; later comb             12386304
  u16*  vt    = (u16*)(ws + 49717248);       // v^T; later vst                    11796480
  u16*  hsB   = (u16*)(ws + 61513728);       // self-attn out bf16                11796480

  maskdet     <<<dim3(1),       256, 0, stream>>>((const u32*)mid, mode);
  maskprep    <<<dim3(18),      256, 0, stream>>>(mid, mig, mk, mg, mode);
  transpose_w <<<dim3(40,40,4), 256, 0, stream>>>(Wq, Wk, Wv, Wo, WT);
  conv        <<<dim3(2880),    256, 0, stream>>>(hid, slotA, 5898240);            // hidB
  gemm128     <<<dim3(36,10,3), 256, 0, stream>>>(slotA, WT, q, slotB, vt, nullptr, nullptr, 0);
  convK       <<<dim3(6048),    256, 0, stream>>>(sks, slotA);                     // hidB dead -> sksP
  attn        <<<dim3(18,16),   512, 0, stream>>>(q, slotB, vt, nullptr, nullptr, hsB, nullptr, scl, 0);
  transpose_vs<<<dim3(72,5,16), 256, 0, stream>>>(svs, vt);                        // vt dead -> vst
  attn        <<<dim3(18,16),   512, 0, stream>>>(q, slotA, vt, mk, mg, hsB, slotB, scl, 1); // kP dead -> comb
  gemm128     <<<dim3(36,10,1), 256, 0, stream>>>(slotB, WT + (size_t)3*1280*1280,
                                                  nullptr, nullptr, nullptr, (float*)d_out, bo, 1);
}

// Round 6
// 495.017 us; speedup vs baseline: 1.0936x; 1.0936x over previous
//
#include <hip/hip_runtime.h>

// Problem: B=2, S=2304, C=1280, NH=8, DH=160, MH=64, SR=48, BH=16
// R11: 517us (attn 2x131): 4-wave/64q blocks, single-K/V rotated pipeline,
//      3 blocks/CU, no tail. R12: 8-wave/128q REGRESSED (142us): 288 blocks on
//      256 CUs = 1.78x load imbalance + 8-wave barrier skew; but T13
//      defer-rescale cut VALU 38.6->29.6 as designed.
// R13: revert to R11 geometry, KEEP T13 + Ps-early-write. New: (a) exp2-direct
//      softmax - Q pre-scaled by INVS*log2(e) at GEMM epilogue, p=v_exp_f32(sc-m)
//      with zero muls on the exp chain (THR=8 in log2 units -> P<=256, safe);
//      (b) s_setprio(1) around QK^T and PV MFMA clusters (T5; phase-split
//      schedule across 3 resident blocks is the regime where it pays).

typedef unsigned short u16;
typedef unsigned int   u32;
typedef unsigned char  u8;
typedef __attribute__((ext_vector_type(8))) short bf16x8;   // 8 bf16 = 4 VGPRs
typedef __attribute__((ext_vector_type(4))) float f32x4;

#define MFMA16(a,b,c) __builtin_amdgcn_mfma_f32_16x16x32_bf16((a),(b),(c),0,0,0)
#define INVS 0.07905694150420949f                 // 1/sqrt(160)
#define QSCL (0.07905694150420949f * 1.4426950408889634f)   // INVS * log2(e)
#define EXP2(x) __builtin_amdgcn_exp2f(x)
#define KPAD 168                                  // K row stride (u16): 84 dw -> b128 reads at bank floor
#define PSTR 76                                   // Ps row stride (u16): 38 dw -> write quads on distinct banks

typedef const __attribute__((address_space(1))) void gvoid;
typedef __attribute__((address_space(3))) void lvoid;
#define GLD16(gp, lp) __builtin_amdgcn_global_load_lds((gvoid*)(gp), (lvoid*)(lp), 16, 0, 0)

__device__ __forceinline__ u16 f2b(float f) {            // fp32 -> bf16 RNE
  u32 u = __float_as_uint(f);
  return (u16)((u + 0x7fffu + ((u >> 16) & 1u)) >> 16);
}
__device__ __forceinline__ float b2f(u16 v) { return __uint_as_float(((u32)v) << 16); }

// DPP reduction over a 16-lane row (exactly our l16 domain = one DPP row):
// quad_perm(1,0,3,2)=0xB1, quad_perm(2,3,0,1)=0x4E, row_half_mirror=0x141, row_mirror=0x140
#define DPPF(x, ctrl) __int_as_float(__builtin_amdgcn_update_dpp(0, __float_as_int(x), (ctrl), 0xf, 0xf, true))
__device__ __forceinline__ float row_max16(float x) {
  x = fmaxf(x, DPPF(x, 0xB1));
  x = fmaxf(x, DPPF(x, 0x4E));
  x = fmaxf(x, DPPF(x, 0x141));
  x = fmaxf(x, DPPF(x, 0x140));
  return x;
}
__device__ __forceinline__ float row_sum16(float x) {
  x += DPPF(x, 0xB1);
  x += DPPF(x, 0x4E);
  x += DPPF(x, 0x141);
  x += DPPF(x, 0x140);
  return x;
}

// ---------------- mask-mode detector: 0=i32, 1=u8, 2=bf16, 3=f32 ----------------
__global__ __launch_bounds__(256) void maskdet(const u32* __restrict__ mid, u32* mode)
{
  __shared__ int a0, a1, a2, a3;
  int tid = threadIdx.x;
  if (tid == 0) { a0 = 1; a1 = 1; a2 = 1; a3 = 0; }
  __syncthreads();
  #pragma unroll
  for (int j = 0; j < 4; j++) {
    u32 w = mid[tid*4 + j];                      // first 4 KiB, in-bounds for all dtypes
    if (w > 1u)                      atomicAnd(&a0, 0);  // not i32 bools
    if (w & 0xFEFEFEFEu)             atomicAnd(&a1, 0);  // not u8 bools
    if (w != 0u && w != 0x3F800000u) atomicAnd(&a2, 0);  // not f32 {0,1}
    if ((w & 0xFFFFu) == 0x3F80u)    atomicOr(&a3, 1);   // bf16 1.0 in low half
  }
  __syncthreads();
  if (tid == 0) mode[0] = a0 ? 0u : (a1 ? 1u : (a3 ? 2u : (a2 ? 3u : 0u)));
}

// ---------------- nearest-downsample masks 64x64 -> 48x48 flattened to S ----------------
__global__ void maskprep(const void* mid, const float* __restrict__ mig_in,
                         float* __restrict__ mk, float* __restrict__ mg, const u32* mode)
{
  int j = blockIdx.x*256 + threadIdx.x;
  if (j >= 2*2304) return;
  u32 md = mode[0];
  int b = j / 2304, s = j % 2304;
  int i = s / 48, jj = s % 48;
  int ih = (i*4)/3, iw = (jj*4)/3;        // arange(48)*64//48
  int src = b*4096 + ih*64 + iw;
  bool on;
  if      (md == 0) on = ((const int*)mid)[src] != 0;
  else if (md == 1) on = ((const u8*)mid)[src]  != 0;
  else if (md == 2) on = ((const u16*)mid)[src] != 0;
  else              on = ((const float*)mid)[src] != 0.0f;
  mk[j] = on ? 1.0f : 0.0f;
  mg[j] = mig_in[src];                     // mask_ig is fp32
}

// ---------------- transpose weights: fp32 W[k][n] -> bf16 WT[n][k], 4 matrices --------------
__global__ __launch_bounds__(256) void transpose_w(
    const float* __restrict__ W0, const float* __restrict__ W1,
    const float* __restrict__ W2, const float* __restrict__ W3, u16* __restrict__ WT)
{
  __shared__ u16 t[32][33];
  int z = blockIdx.z;
  const float* s = (z==0)?W0:(z==1)?W1:(z==2)?W2:W3;
  u16* d = WT + (size_t)z*1280*1280;
  int tx = threadIdx.x & 31, ty = (threadIdx.x >> 5) * 4;
  int x = blockIdx.x*32 + tx;          // src col (n)
  int y = blockIdx.y*32 + ty;          // src row (k)
  #pragma unroll
  for (int i=0;i<4;i++) t[ty+i][tx] = f2b(s[(size_t)(y+i)*1280 + x]);
  __syncthreads();
  int x2 = blockIdx.y*32 + tx, y2 = blockIdx.x*32 + ty;
  #pragma unroll
  for (int i=0;i<4;i++) d[(size_t)(y2+i)*1280 + x2] = t[tx][ty+i];   // WT[n][k] = W[k][n]
}

// ---------------- convert fp32 -> bf16 (unpadded) ----------------
__global__ __launch_bounds__(256) void conv(const float* __restrict__ src, u16* __restrict__ dst, int n)
{
  for (int i = blockIdx.x*256 + threadIdx.x; i < n; i += gridDim.x*256)
    dst[i] = f2b(src[i]);
}

// ---------------- convert store_ks fp32 [bh][s][160] -> padded bf16 [bh][s][168] ------------
__global__ __launch_bounds__(256) void convK(const float* __restrict__ src, u16* __restrict__ dst)
{
  const int n = 16*2304*KPAD;
  for (int i = blockIdx.x*256 + threadIdx.x; i < n; i += gridDim.x*256) {
    int row = i / KPAD, col = i % KPAD;
    dst[i] = (col < 160) ? f2b(src[(size_t)row*160 + col]) : (u16)0;
  }
}

// ---------------- transpose store_vs fp32 [16][2304][160] -> bf16 vst[16][160][2304] ---------
__global__ __launch_bounds__(256) void transpose_vs(const float* __restrict__ src, u16* __restrict__ dst)
{
  __shared__ u16 t[32][33];
  int z = blockIdx.z;
  u16* d = dst + (size_t)z*160*2304;
  int tx = threadIdx.x & 31, ty = (threadIdx.x >> 5) * 4;
  int r0 = blockIdx.x*32, c0 = blockIdx.y*32;
  #pragma unroll
  for (int i=0;i<4;i++)
    t[ty+i][tx] = f2b(src[((size_t)z*2304 + r0+ty+i)*160 + c0+tx]);
  __syncthreads();
  #pragma unroll
  for (int i=0;i<4;i++) d[(size_t)(c0+ty+i)*2304 + r0+tx] = t[tx][ty+i]; // d[c][r] = s[r][c]
}

// ---------------- GEMM: 128x128 tile, BK=32, 4 waves (2x2), 16x16x32 MFMA ----------------
// kind 0: A=hidB, BT=WT[z]; z=0->q*QSCL [bh][s][160], z=1->k PADDED [bh][s][168], z=2->v^T [bh][d][s]
// kind 1: A=comb, BT=WoT;   out = A@Wo + bias -> fp32 d_out
__global__ __launch_bounds__(256, 2) void gemm128(
    const u16* __restrict__ A, const u16* __restrict__ BT,
    u16* __restrict__ dq, u16* __restrict__ dk, u16* __restrict__ dvt,
    float* __restrict__ dout, const float* __restrict__ bias, int kind)
{
  __shared__ __align__(16) u16 As[128*40];   // pad 32->40: 80B stride breaks conflicts
  __shared__ __align__(16) u16 Bs[128*40];
  int tid = threadIdx.x;
  int m0 = blockIdx.x*128, n0 = blockIdx.y*128;
  int z = blockIdx.z;
  const u16* Bt = BT + (size_t)z*1280*1280;
  int w = tid>>6, lane = tid&63, quad = lane>>4, l16 = lane&15;
  int wm = w&1, wn = w>>1;
  int arow = tid>>1, acg = (tid&1)*16;
  f32x4 zero = {0.f,0.f,0.f,0.f};
  f32x4 acc[4][4];
  #pragma unroll
  for (int a=0;a<4;a++) { acc[a][0]=zero; acc[a][1]=zero; acc[a][2]=zero; acc[a][3]=zero; }
  const u16* ga = A  + (size_t)(m0+arow)*1280 + acg;
  const u16* gb = Bt + (size_t)(n0+arow)*1280 + acg;
  for (int k0 = 0; k0 < 1280; k0 += 32) {
    uint4 a0 = *(const uint4*)(ga + k0);
    uint4 a1 = *(const uint4*)(ga + k0 + 8);
    uint4 b0 = *(const uint4*)(gb + k0);
    uint4 b1 = *(const uint4*)(gb + k0 + 8);
    __syncthreads();
    *(uint4*)&As[arow*40 + acg]     = a0;
    *(uint4*)&As[arow*40 + acg + 8] = a1;
    *(uint4*)&Bs[arow*40 + acg]     = b0;
    *(uint4*)&Bs[arow*40 + acg + 8] = b1;
    __syncthreads();
    bf16x8 af[4], bfr[4];
    #pragma unroll
    for (int mt=0; mt<4; mt++) af[mt]  = *(const bf16x8*)&As[(wm*64+mt*16+l16)*40 + quad*8];
    #pragma unroll
    for (int nt=0; nt<4; nt++) bfr[nt] = *(const bf16x8*)&Bs[(wn*64+nt*16+l16)*40 + quad*8];
    #pragma unroll
    for (int mt=0; mt<4; mt++)
      #pragma unroll
      for (int nt=0; nt<4; nt++)
        acc[mt][nt] = MFMA16(af[mt], bfr[nt], acc[mt][nt]);
  }
  #pragma unroll
  for (int mt=0; mt<4; mt++) {
    int r0g = m0 + wm*64 + mt*16 + quad*4;          // 4 consecutive rows (reg 0..3)
    #pragma unroll
    for (int nt=0; nt<4; nt++) {
      int col = n0 + wn*64 + nt*16 + l16;
      if (kind == 1) {
        float bi = bias[col];
        #pragma unroll
        for (int r=0;r<4;r++) dout[(size_t)(r0g+r)*1280 + col] = acc[mt][nt][r] + bi;
      } else {
        int h = col/160, d = col%160;
        if (z == 2) {                               // v -> [bh][d][s], s consecutive
          int b = r0g/2304, s0 = r0g%2304;
          size_t base = ((size_t)((b*8+h)*160 + d))*2304 + s0;
          ushort4 pk;
          pk.x = f2b(acc[mt][nt][0]); pk.y = f2b(acc[mt][nt][1]);
          pk.z = f2b(acc[mt][nt][2]); pk.w = f2b(acc[mt][nt][3]);
          *(ushort4*)&dvt[base] = pk;
        } else {
          #pragma unroll
          for (int r=0;r<4;r++) {
            int rg = r0g + r;
            int b = rg/2304, s = rg%2304;
            if (z == 0) dq[((size_t)(b*8+h)*2304 + s)*160  + d] = f2b(acc[mt][nt][r] * QSCL);
            else        dk[((size_t)(b*8+h)*2304 + s)*KPAD + d] = f2b(acc[mt][nt][r]);
          }
        }
      }
    }
  }
}

// ---------------- Attention (flash-style, online softmax in log2 domain). -------------
// ip=0: self -> hs (bf16). ip=1: keys=sksP, V=vst, per-key mask, combine -> comb bf16.
// SINGLE-buffered K and V, rotated pipeline:
//   QK^T(kc) | barA (Ks consumed, V(kc) drained) | issue K(kc+1)
//   softmax(T13 defer, exp2-direct)+Ps+PV(kc) (covers K DMA) | barB | issue V(kc+1).
// LDS 51.7KB -> 3 blocks/CU, all 576 blocks resident. Q pre-scaled by INVS*log2e.
// K: lane-linear DMA of padded rows. V: per-lane-source DMA, XOR granule swizzle.
__global__ __launch_bounds__(256, 3) void attn(
    const u16* __restrict__ qg,   // [16][2304][160], pre-scaled by QSCL
    const u16* __restrict__ kg,   // PADDED [16][2304][168]
    const u16* __restrict__ vtg,  // [16][160][2304]
    const float* __restrict__ maskkey, const float* __restrict__ mig,
    u16* __restrict__ hs, u16* __restrict__ comb,
    const void* scaleptr, int ip)
{
  __shared__ __align__(16) u16 Ks[64*KPAD];     // 21504 B single buffer
  __shared__ __align__(16) u16 Vs[160*64];      // 20480 B, XOR-swizzled granules
  __shared__ __align__(16) u16 Ps[4*16*PSTR];   // 9728 B per-wave P relayout
  // XCD-aware remap: linear dispatch id round-robins XCDs (id%8). Give XCD c
  // bh {2c, 2c+1} so its working set (K 774KB + V 737KB per bh) fits 4MB L2.
  int id = blockIdx.y*36 + blockIdx.x;
  int xc = id & 7, kq = id >> 3;                 // kq in 0..71
  int bh = 2*xc + (kq >= 36 ? 1 : 0);
  int qt = (kq >= 36) ? kq - 36 : kq;
  int tid = threadIdx.x, w = tid>>6, lane = tid&63, quad = lane>>4, l16 = lane&15;
  int q0 = qt*64 + w*16;                         // wave's 16 queries

  const char* kgbytes = (const char*)kg;
  const char* ktile0 = kgbytes + ((size_t)bh*2304)*(KPAD*2);
  const char* vbytes = (const char*)vtg + ((size_t)bh*160)*2304*2;  // V^T slice base

  // V DMA lane geometry: instr j covers d-rows [j*8, j*8+8), 8 lanes per row.
  // Lane l fetches global granule ((l&7)^(l>>3)) of row j*8+(l>>3); LDS image
  // then has granule g of row d at byte d*128 + (g^(d&7))*16.
  int vrowl = lane>>3;                          // local d row 0..7
  int vgsw  = ((lane&7) ^ vrowl) << 4;          // swizzled source byte offset

  // ---- prologue: issue K(0) + V(0) DMA (both drained by the pre-loop barrier) ----
  {
    char* dst = (char*)Ks;
    int off = w*1024 + lane*16;
    #pragma unroll
    for (int j=0;j<5;j++) GLD16(ktile0 + j*4096 + off, dst + j*4096 + w*1024);
    if (w == 0) GLD16(ktile0 + 20480 + lane*16, dst + 20480);  // 21504-20480 tail
    #pragma unroll
    for (int j5=0;j5<5;j5++) {
      int j = w*5 + j5;
      GLD16(vbytes + (size_t)(j*8 + vrowl)*4608 + vgsw, (char*)Vs + j*1024);
    }
  }

  bf16x8 aq[5];                                // Q frags: A[m=l16][k=quad*8+j], 5 ksteps
  {
    const u16* qrow = qg + ((size_t)bh*2304 + q0 + l16)*160 + quad*8;
    #pragma unroll
    for (int ks=0; ks<5; ks++) aq[ks] = *(const bf16x8*)(qrow + ks*32);
  }
  f32x4 zero = {0.f,0.f,0.f,0.f};
  f32x4 o[10];
  #pragma unroll
  for (int i=0;i<10;i++) o[i] = zero;
  float mrun[4] = {-1e30f,-1e30f,-1e30f,-1e30f};
  float lrun[4] = {0.f,0.f,0.f,0.f};

  const float* mkb = ip ? (maskkey + (bh & 1)*2304) : nullptr;
  float mcur[4] = {1.f,1.f,1.f,1.f};
  if (ip) {
    #pragma unroll
    for (int nt=0;nt<4;nt++) mcur[nt] = mkb[nt*16 + l16];
  }

  __syncthreads();                             // drains K(0)+V(0)+Q loads

  for (int kc = 0; kc < 36; kc++) {
    // ---- prefetch next iteration's mask values (off the score critical path) ----
    float mnxt[4] = {1.f,1.f,1.f,1.f};
    if (ip && kc < 35) {
      #pragma unroll
      for (int nt=0;nt<4;nt++) mnxt[nt] = mkb[(kc+1)*64 + nt*16 + l16];
    }

    // ---- scores S[16 q][64 keys] = Q K^T (log2 units), K from LDS ----
    f32x4 sc[4];
    bool keep[4];
    __builtin_amdgcn_s_setprio(1);
    #pragma unroll
    for (int nt=0; nt<4; nt++) {
      f32x4 s = zero;
      #pragma unroll
      for (int ks=0; ks<5; ks++) {
        bf16x8 bk = *(const bf16x8*)&Ks[(nt*16+l16)*KPAD + ks*32 + quad*8];
        s = MFMA16(aq[ks], bk, s);
      }
      keep[nt] = true;
      if (ip && mcur[nt] == 0.0f) {
        keep[nt] = false;
        #pragma unroll
        for (int r=0;r<4;r++) s[r] = -1e30f;
      }
      sc[nt] = s;
    }
    __builtin_amdgcn_s_setprio(0);

    __syncthreads();                           // barA: Ks consumed by all waves

    // ---- issue K(kc+1) DMA into the (now free) single K buffer; drains at barB ----
    if (kc < 35) {
      const char* tile = ktile0 + (size_t)(kc+1)*64*(KPAD*2);
      char* dst = (char*)Ks;
      int off = w*1024 + lane*16;
      #pragma unroll
      for (int j=0;j<5;j++) GLD16(tile + j*4096 + off, dst + j*4096 + w*1024);
      if (w == 0) GLD16(tile + 20480 + lane*16, dst + 20480);
    }

    // ---- T13 defer-rescale softmax (row = quad*4+r), exp2 domain. Rescale only
    //      when some row's tile-max exceeds mrun+8 (rare). Exact in f32.
    float mrow[4];
    #pragma unroll
    for (int r=0;r<4;r++) {
      float mr = fmaxf(fmaxf(sc[0][r], sc[1][r]), fmaxf(sc[2][r], sc[3][r]));
      mrow[r] = row_max16(mr);
    }
    bool fastok = (mrow[0] <= mrun[0]+8.f) & (mrow[1] <= mrun[1]+8.f)
                & (mrow[2] <= mrun[2]+8.f) & (mrow[3] <= mrun[3]+8.f);
    if (!__all(fastok)) {                      // slow path: grow max, rescale o/l
      #pragma unroll
      for (int r=0;r<4;r++) {
        float nm = fmaxf(mrun[r], mrow[r]);
        float alpha = EXP2(fminf(mrun[r] - nm, 0.f));
        mrun[r] = nm;
        lrun[r] *= alpha;
        #pragma unroll
        for (int nt2=0; nt2<10; nt2++) o[nt2][r] *= alpha;
      }
    }
    // p = exp2(sc - mrun) (bounded by 2^8); write Ps immediately (PV operand)
    float p[4][4];
    #pragma unroll
    for (int nt=0;nt<4;nt++)
      #pragma unroll
      for (int r=0;r<4;r++) {
        float e = keep[nt] ? EXP2(sc[nt][r] - mrun[r]) : 0.f;
        p[nt][r] = e;
        Ps[(w*16 + quad*4 + r)*PSTR + nt*16 + l16] = f2b(e);
      }
    #pragma unroll
    for (int r=0;r<4;r++) {
      float rs = (p[0][r]+p[1][r]) + (p[2][r]+p[3][r]);
      rs = row_sum16(rs);
      lrun[r] += rs;
    }

    // ---- O += P V, V B-frags from LDS (XOR-swizzled, bank-floor b128 reads) ----
    __builtin_amdgcn_s_setprio(1);
    #pragma unroll
    for (int kb=0; kb<2; kb++) {
      bf16x8 ap = *(const bf16x8*)&Ps[(w*16 + l16)*PSTR + kb*32 + quad*8];
      #pragma unroll
      for (int nt=0; nt<10; nt++) {
        int d = nt*16 + l16;
        bf16x8 bv = *(const bf16x8*)((const char*)Vs + d*128 + (((kb*4 + quad) ^ (l16 & 7)) << 4));
        o[nt] = MFMA16(ap, bv, o[nt]);
      }
    }
    __builtin_amdgcn_s_setprio(0);

    if (ip) {
      #pragma unroll
      for (int nt=0;nt<4;nt++) mcur[nt] = mnxt[nt];
    }

    __syncthreads();                           // barB: K(kc+1) drained; Vs consumed by all

    // ---- issue V(kc+1) DMA (drains at next iter's barA, covered by QK^T +
    //      cross-block overlap at 3 blocks/CU) ----
    if (kc < 35) {
      const char* vsrc = vbytes + (size_t)(kc+1)*128;   // key-col offset (kc+1)*64 keys *2B
      #pragma unroll
      for (int j5=0;j5<5;j5++) {
        int j = w*5 + j5;
        GLD16(vsrc + (size_t)(j*8 + vrowl)*4608 + vgsw, (char*)Vs + j*1024);
      }
    }
  }

  // ---- epilogue ----
  int b = bh>>3, h = bh&7;
  float scl = 0.f;
  if (ip) {                                   // scalar dtype self-detect (0.5 decodes both ways)
    u16 v0 = ((const u16*)scaleptr)[0];
    int e = (v0 >> 7) & 0xFF;
    scl = (v0 != 0 && e >= 100 && e <= 133) ? b2f(v0) : ((const float*)scaleptr)[0];
  }
  #pragma unroll
  for (int r=0;r<4;r++) {
    int s = q0 + quad*4 + r;
    float linv = (lrun[r] > 0.f) ? 1.0f/lrun[r] : 0.f;
    size_t base = ((size_t)b*2304 + s)*1280 + h*160;
    if (!ip) {
      #pragma unroll
      for (int nt=0;nt<10;nt++) hs[base + nt*16 + l16] = f2b(o[nt][r]*linv);
    } else {
      float f = mig[b*2304 + s]*scl*linv;    // mig uses TRUE b
      #pragma unroll
      for (int nt=0;nt<10;nt++)
        comb[base + nt*16 + l16] = f2b(b2f(hs[base + nt*16 + l16]) + o[nt][r]*f);
    }
  }
}

// ---------------- launch ----------------
extern "C" void kernel_launch(void* const* d_in, const int* in_sizes, int n_in,
                              void* d_out, int out_size, void* d_ws, size_t ws_size,
                              hipStream_t stream)
{
  const float* hid = (const float*)d_in[0];
  const float* Wq  = (const float*)d_in[1];
  const float* Wk  = (const float*)d_in[2];
  const float* Wv  = (const float*)d_in[3];
  const float* Wo  = (const float*)d_in[4];
  const float* bo  = (const float*)d_in[5];
  const float* sks = (const float*)d_in[6];
  const float* svs = (const float*)d_in[7];
  const void*  mid = d_in[8];
  const float* mig = (const float*)d_in[9];
  const void*  scl = d_in[10];

  char* ws = (char*)d_ws;                    // 69.9 MiB total (aliased, stream-ordered)
  float* mk   = (float*)(ws);                // [2][2304]              18432 B
  float* mg   = (float*)(ws + 18432);        // [2][2304]              18432 B
  u32*  mode  = (u32*)(ws + 36864);          // 256 B
  u16*  WT    = (u16*)(ws + 40960);          // 4 x 1280x1280 bf16  13107200 B
  u16*  slotA = (u16*)(ws + 13148160);       // hidB unpadded; later sksP padded  12386304
  u16*  q     = (u16*)(ws + 25534464);       // [16][2304][160] (pre-scaled)      11796480
  u16*  slotB = (u16*)(ws + 37330944);       // kP padded; later comb             12386304
  u16*  vt    = (u16*)(ws + 49717248);       // v^T; later vst                    11796480
  u16*  hsB   = (u16*)(ws + 61513728);       // self-attn out bf16                11796480

  maskdet     <<<dim3(1),       256, 0, stream>>>((const u32*)mid, mode);
  maskprep    <<<dim3(18),      256, 0, stream>>>(mid, mig, mk, mg, mode);
  transpose_w <<<dim3(40,40,4), 256, 0, stream>>>(Wq, Wk, Wv, Wo, WT);
  conv        <<<dim3(2880),    256, 0, stream>>>(hid, slotA, 5898240);            // hidB
  gemm128     <<<dim3(36,10,3), 256, 0, stream>>>(slotA, WT, q, slotB, vt, nullptr, nullptr, 0);
  convK       <<<dim3(6048),    256, 0, stream>>>(sks, slotA);                     // hidB dead -> sksP
  attn        <<<dim3(36,16),   256, 0, stream>>>(q, slotB, vt, nullptr, nullptr, hsB, nullptr, scl, 0);
  transpose_vs<<<dim3(72,5,16), 256, 0, stream>>>(svs, vt);                        // vt dead -> vst
  attn        <<<dim3(36,16),   256, 0, stream>>>(q, slotA, vt, mk, mg, hsB, slotB, scl, 1); // kP dead -> comb
  gemm128     <<<dim3(36,10,1), 256, 0, stream>>>(slotB, WT + (size_t)3*1280*1280,
                                                  nullptr, nullptr, nullptr, (float*)d_out, bo, 1);
}

// Round 7
// 488.819 us; speedup vs baseline: 1.1074x; 1.0127x over previous
//
#include <hip/hip_runtime.h>

// Problem: B=2, S=2304, C=1280, NH=8, DH=160, MH=64, SR=48, BH=16
// R13: 495us. attn 2x119.8 (MfmaUtil 19, VALU 36) - exp2+T13+setprio on the
//      4-wave rotated pipeline. Non-attn half now ~255us; QKV GEMM (est ~100us,
//      VGPR-transit staging, 2 blocks/CU) is the largest non-attn item.
// R14: (a) gemm128 staging -> global_load_lds DMA (m97 pattern, the guide's
//      proven +69% lever), per-lane sources map into padded [128][40] LDS;
//      __launch_bounds__(256,3) -> 3 blocks/CU. (b) convK ELIMINATED: K kept
//      unpadded [bh][s][160] everywhere; attn K tiles are contiguous 20480B,
//      staged via GLD16 with XOR-swizzled per-lane sources (bank-free b128
//      reads, verified per-group). Attn softmax/pipeline unchanged from R13.

typedef unsigned short u16;
typedef unsigned int   u32;
typedef unsigned char  u8;
typedef __attribute__((ext_vector_type(8))) short bf16x8;   // 8 bf16 = 4 VGPRs
typedef __attribute__((ext_vector_type(4))) float f32x4;

#define MFMA16(a,b,c) __builtin_amdgcn_mfma_f32_16x16x32_bf16((a),(b),(c),0,0,0)
#define INVS 0.07905694150420949f                 // 1/sqrt(160)
#define QSCL (0.07905694150420949f * 1.4426950408889634f)   // INVS * log2(e)
#define EXP2(x) __builtin_amdgcn_exp2f(x)
#define PSTR 76                                   // Ps row stride (u16): 38 dw -> write quads on distinct banks

typedef const __attribute__((address_space(1))) void gvoid;
typedef __attribute__((address_space(3))) void lvoid;
#define GLD16(gp, lp) __builtin_amdgcn_global_load_lds((gvoid*)(gp), (lvoid*)(lp), 16, 0, 0)

__device__ __forceinline__ u16 f2b(float f) {            // fp32 -> bf16 RNE
  u32 u = __float_as_uint(f);
  return (u16)((u + 0x7fffu + ((u >> 16) & 1u)) >> 16);
}
__device__ __forceinline__ float b2f(u16 v) { return __uint_as_float(((u32)v) << 16); }

// DPP reduction over a 16-lane row (exactly our l16 domain = one DPP row):
#define DPPF(x, ctrl) __int_as_float(__builtin_amdgcn_update_dpp(0, __float_as_int(x), (ctrl), 0xf, 0xf, true))
__device__ __forceinline__ float row_max16(float x) {
  x = fmaxf(x, DPPF(x, 0xB1));
  x = fmaxf(x, DPPF(x, 0x4E));
  x = fmaxf(x, DPPF(x, 0x141));
  x = fmaxf(x, DPPF(x, 0x140));
  return x;
}
__device__ __forceinline__ float row_sum16(float x) {
  x += DPPF(x, 0xB1);
  x += DPPF(x, 0x4E);
  x += DPPF(x, 0x141);
  x += DPPF(x, 0x140);
  return x;
}

// ---------------- mask-mode detector: 0=i32, 1=u8, 2=bf16, 3=f32 ----------------
__global__ __launch_bounds__(256) void maskdet(const u32* __restrict__ mid, u32* mode)
{
  __shared__ int a0, a1, a2, a3;
  int tid = threadIdx.x;
  if (tid == 0) { a0 = 1; a1 = 1; a2 = 1; a3 = 0; }
  __syncthreads();
  #pragma unroll
  for (int j = 0; j < 4; j++) {
    u32 w = mid[tid*4 + j];                      // first 4 KiB, in-bounds for all dtypes
    if (w > 1u)                      atomicAnd(&a0, 0);  // not i32 bools
    if (w & 0xFEFEFEFEu)             atomicAnd(&a1, 0);  // not u8 bools
    if (w != 0u && w != 0x3F800000u) atomicAnd(&a2, 0);  // not f32 {0,1}
    if ((w & 0xFFFFu) == 0x3F80u)    atomicOr(&a3, 1);   // bf16 1.0 in low half
  }
  __syncthreads();
  if (tid == 0) mode[0] = a0 ? 0u : (a1 ? 1u : (a3 ? 2u : (a2 ? 3u : 0u)));
}

// ---------------- nearest-downsample masks 64x64 -> 48x48 flattened to S ----------------
__global__ void maskprep(const void* mid, const float* __restrict__ mig_in,
                         float* __restrict__ mk, float* __restrict__ mg, const u32* mode)
{
  int j = blockIdx.x*256 + threadIdx.x;
  if (j >= 2*2304) return;
  u32 md = mode[0];
  int b = j / 2304, s = j % 2304;
  int i = s / 48, jj = s % 48;
  int ih = (i*4)/3, iw = (jj*4)/3;        // arange(48)*64//48
  int src = b*4096 + ih*64 + iw;
  bool on;
  if      (md == 0) on = ((const int*)mid)[src] != 0;
  else if (md == 1) on = ((const u8*)mid)[src]  != 0;
  else if (md == 2) on = ((const u16*)mid)[src] != 0;
  else              on = ((const float*)mid)[src] != 0.0f;
  mk[j] = on ? 1.0f : 0.0f;
  mg[j] = mig_in[src];                     // mask_ig is fp32
}

// ---------------- transpose weights: fp32 W[k][n] -> bf16 WT[n][k], 4 matrices --------------
__global__ __launch_bounds__(256) void transpose_w(
    const float* __restrict__ W0, const float* __restrict__ W1,
    const float* __restrict__ W2, const float* __restrict__ W3, u16* __restrict__ WT)
{
  __shared__ u16 t[32][33];
  int z = blockIdx.z;
  const float* s = (z==0)?W0:(z==1)?W1:(z==2)?W2:W3;
  u16* d = WT + (size_t)z*1280*1280;
  int tx = threadIdx.x & 31, ty = (threadIdx.x >> 5) * 4;
  int x = blockIdx.x*32 + tx;          // src col (n)
  int y = blockIdx.y*32 + ty;          // src row (k)
  #pragma unroll
  for (int i=0;i<4;i++) t[ty+i][tx] = f2b(s[(size_t)(y+i)*1280 + x]);
  __syncthreads();
  int x2 = blockIdx.y*32 + tx, y2 = blockIdx.x*32 + ty;
  #pragma unroll
  for (int i=0;i<4;i++) d[(size_t)(y2+i)*1280 + x2] = t[tx][ty+i];   // WT[n][k] = W[k][n]
}

// ---------------- convert fp32 -> bf16 (unpadded) ----------------
__global__ __launch_bounds__(256) void conv(const float* __restrict__ src, u16* __restrict__ dst, int n)
{
  for (int i = blockIdx.x*256 + threadIdx.x; i < n; i += gridDim.x*256)
    dst[i] = f2b(src[i]);
}

// ---------------- transpose store_vs fp32 [16][2304][160] -> bf16 vst[16][160][2304] ---------
__global__ __launch_bounds__(256) void transpose_vs(const float* __restrict__ src, u16* __restrict__ dst)
{
  __shared__ u16 t[32][33];
  int z = blockIdx.z;
  u16* d = dst + (size_t)z*160*2304;
  int tx = threadIdx.x & 31, ty = (threadIdx.x >> 5) * 4;
  int r0 = blockIdx.x*32, c0 = blockIdx.y*32;
  #pragma unroll
  for (int i=0;i<4;i++)
    t[ty+i][tx] = f2b(src[((size_t)z*2304 + r0+ty+i)*160 + c0+tx]);
  __syncthreads();
  #pragma unroll
  for (int i=0;i<4;i++) d[(size_t)(c0+ty+i)*2304 + r0+tx] = t[tx][ty+i]; // d[c][r] = s[r][c]
}

// ---------------- GEMM: 128x128 tile, BK=32, 4 waves (2x2), 16x16x32 MFMA ----------------
// Staging via global_load_lds (m97 pattern): per-lane SOURCE offsets place the
// lane-linear LDS image into padded [128][40 u16] rows (pad granules fetch row
// start, never read). 2 barriers/iter; 3 blocks/CU.
// kind 0: A=hidB, BT=WT[z]; z=0->q*QSCL [bh][s][160], z=1->k [bh][s][160], z=2->v^T [bh][d][s]
// kind 1: A=comb, BT=WoT;   out = A@Wo + bias -> fp32 d_out
__global__ __launch_bounds__(256, 3) void gemm128(
    const u16* __restrict__ A, const u16* __restrict__ BT,
    u16* __restrict__ dq, u16* __restrict__ dk, u16* __restrict__ dvt,
    float* __restrict__ dout, const float* __restrict__ bias, int kind)
{
  __shared__ __align__(16) u16 S[2*128*40];  // As | Bs, 20480 B total
  int tid = threadIdx.x;
  int m0 = blockIdx.x*128, n0 = blockIdx.y*128;
  int z = blockIdx.z;
  const u16* Bt = BT + (size_t)z*1280*1280;
  int w = tid>>6, lane = tid&63, quad = lane>>4, l16 = lane&15;
  int wm = w&1, wn = w>>1;
  // per-thread staging sources: dest granule G = j*256+tid -> LDS byte p=G*16;
  // mat = p/10240 (0=A,1=B); prow = (p%10240)/80; pcol = p%80 (>=64 -> pad).
  const char* ga = (const char*)(A  + (size_t)m0*1280);
  const char* gb = (const char*)(Bt + (size_t)n0*1280);
  const char* sp[5];
  #pragma unroll
  for (int j=0;j<5;j++) {
    int p = j*4096 + tid*16;
    int mat = p / 10240;
    int q2 = p - mat*10240;
    int prow = q2 / 80, pcol = q2 - prow*80;
    int so = prow*2560 + (pcol < 64 ? pcol : 0);
    sp[j] = (mat ? gb : ga) + so;
  }
  char* ldst = (char*)S + w*1024;            // wave-uniform dest (HW adds lane*16)
  f32x4 zero = {0.f,0.f,0.f,0.f};
  f32x4 acc[4][4];
  #pragma unroll
  for (int a=0;a<4;a++) { acc[a][0]=zero; acc[a][1]=zero; acc[a][2]=zero; acc[a][3]=zero; }
  for (int k0b = 0; k0b < 2560; k0b += 64) { // byte offset along K (32 u16/step)
    __syncthreads();                         // prior iter's LDS reads complete
    #pragma unroll
    for (int j=0;j<5;j++) GLD16(sp[j] + k0b, ldst + j*4096);
    __syncthreads();                         // drains own vmcnt -> tile ready
    bf16x8 af[4], bfr[4];
    #pragma unroll
    for (int mt=0; mt<4; mt++) af[mt]  = *(const bf16x8*)&S[(wm*64+mt*16+l16)*40 + quad*8];
    #pragma unroll
    for (int nt=0; nt<4; nt++) bfr[nt] = *(const bf16x8*)&S[128*40 + (wn*64+nt*16+l16)*40 + quad*8];
    __builtin_amdgcn_s_setprio(1);
    #pragma unroll
    for (int mt=0; mt<4; mt++)
      #pragma unroll
      for (int nt=0; nt<4; nt++)
        acc[mt][nt] = MFMA16(af[mt], bfr[nt], acc[mt][nt]);
    __builtin_amdgcn_s_setprio(0);
  }
  #pragma unroll
  for (int mt=0; mt<4; mt++) {
    int r0g = m0 + wm*64 + mt*16 + quad*4;          // 4 consecutive rows (reg 0..3)
    #pragma unroll
    for (int nt=0; nt<4; nt++) {
      int col = n0 + wn*64 + nt*16 + l16;
      if (kind == 1) {
        float bi = bias[col];
        #pragma unroll
        for (int r=0;r<4;r++) dout[(size_t)(r0g+r)*1280 + col] = acc[mt][nt][r] + bi;
      } else {
        int h = col/160, d = col%160;
        if (z == 2) {                               // v -> [bh][d][s], s consecutive
          int b = r0g/2304, s0 = r0g%2304;
          size_t base = ((size_t)((b*8+h)*160 + d))*2304 + s0;
          ushort4 pk;
          pk.x = f2b(acc[mt][nt][0]); pk.y = f2b(acc[mt][nt][1]);
          pk.z = f2b(acc[mt][nt][2]); pk.w = f2b(acc[mt][nt][3]);
          *(ushort4*)&dvt[base] = pk;
        } else {
          #pragma unroll
          for (int r=0;r<4;r++) {
            int rg = r0g + r;
            int b = rg/2304, s = rg%2304;
            if (z == 0) dq[((size_t)(b*8+h)*2304 + s)*160 + d] = f2b(acc[mt][nt][r] * QSCL);
            else        dk[((size_t)(b*8+h)*2304 + s)*160 + d] = f2b(acc[mt][nt][r]);
          }
        }
      }
    }
  }
}

// ---------------- Attention (flash-style, online softmax in log2 domain). -------------
// ip=0: self -> hs (bf16). ip=1: keys=sksB, V=vst, per-key mask, combine -> comb bf16.
// SINGLE-buffered K and V, rotated pipeline:
//   QK^T(kc) | barA (Ks consumed, V(kc) drained) | issue K(kc+1)
//   softmax(T13 defer, exp2-direct)+Ps+PV(kc) (covers K DMA) | barB | issue V(kc+1).
// K UNPADDED [bh][s][160]: tile kc is a contiguous 20480B block, staged by GLD16
// with XOR-swizzled per-lane sources: row r, 16B granule g stored at slot
//   g<16: (g&8)|((g&7)^(r&7));  g>=16: 16+((g&3)^((r>>1)&3))
// -> b128 QK^T reads land 2 lanes/bank (free). V: same scheme as R10.
// LDS 50.7KB -> 3 blocks/CU, all 576 blocks resident. Q pre-scaled by INVS*log2e.
__global__ __launch_bounds__(256, 3) void attn(
    const u16* __restrict__ qg,   // [16][2304][160], pre-scaled by QSCL
    const u16* __restrict__ kg,   // [16][2304][160] unpadded
    const u16* __restrict__ vtg,  // [16][160][2304]
    const float* __restrict__ maskkey, const float* __restrict__ mig,
    u16* __restrict__ hs, u16* __restrict__ comb,
    const void* scaleptr, int ip)
{
  __shared__ __align__(16) u16 Ks[64*160];      // 20480 B, XOR-swizzled granules
  __shared__ __align__(16) u16 Vs[160*64];      // 20480 B, XOR-swizzled granules
  __shared__ __align__(16) u16 Ps[4*16*PSTR];   // 9728 B per-wave P relayout
  // XCD-aware remap: linear dispatch id round-robins XCDs (id%8). Give XCD c
  // bh {2c, 2c+1} so its working set (K+V ~1.5MB per bh) fits 4MB L2.
  int id = blockIdx.y*36 + blockIdx.x;
  int xc = id & 7, kq = id >> 3;                 // kq in 0..71
  int bh = 2*xc + (kq >= 36 ? 1 : 0);
  int qt = (kq >= 36) ? kq - 36 : kq;
  int tid = threadIdx.x, w = tid>>6, lane = tid&63, quad = lane>>4, l16 = lane&15;
  int q0 = qt*64 + w*16;                         // wave's 16 queries

  const char* kbase = (const char*)kg + (size_t)bh*2304*320;
  const char* vbytes = (const char*)vtg + ((size_t)bh*160)*2304*2;  // V^T slice base

  // K DMA per-thread swizzled source offsets (dest granule G = j*256+tid):
  u32 ksrc[5];
  #pragma unroll
  for (int j=0;j<5;j++) {
    int G = j*256 + tid;
    int row = G/20, slot = G - row*20;
    int g = (slot < 16) ? ((slot&8)|((slot&7)^(row&7)))
                        : (16 + ((slot&3)^((row>>1)&3)));
    ksrc[j] = row*320 + g*16;
  }
  char* kdst = (char*)Ks + w*1024;               // wave-uniform dest (HW adds lane*16)

  // V DMA lane geometry: instr j covers d-rows [j*8, j*8+8), 8 lanes per row.
  int vrowl = lane>>3;                          // local d row 0..7
  int vgsw  = ((lane&7) ^ vrowl) << 4;          // swizzled source byte offset

  // ---- prologue: issue K(0) + V(0) DMA (both drained by the pre-loop barrier) ----
  {
    #pragma unroll
    for (int j=0;j<5;j++) GLD16(kbase + ksrc[j], kdst + j*4096);
    #pragma unroll
    for (int j5=0;j5<5;j5++) {
      int j = w*5 + j5;
      GLD16(vbytes + (size_t)(j*8 + vrowl)*4608 + vgsw, (char*)Vs + j*1024);
    }
  }

  bf16x8 aq[5];                                // Q frags: A[m=l16][k=quad*8+j], 5 ksteps
  {
    const u16* qrow = qg + ((size_t)bh*2304 + q0 + l16)*160 + quad*8;
    #pragma unroll
    for (int ks=0; ks<5; ks++) aq[ks] = *(const bf16x8*)(qrow + ks*32);
  }
  f32x4 zero = {0.f,0.f,0.f,0.f};
  f32x4 o[10];
  #pragma unroll
  for (int i=0;i<10;i++) o[i] = zero;
  float mrun[4] = {-1e30f,-1e30f,-1e30f,-1e30f};
  float lrun[4] = {0.f,0.f,0.f,0.f};

  const float* mkb = ip ? (maskkey + (bh & 1)*2304) : nullptr;
  float mcur[4] = {1.f,1.f,1.f,1.f};
  if (ip) {
    #pragma unroll
    for (int nt=0;nt<4;nt++) mcur[nt] = mkb[nt*16 + l16];
  }

  __syncthreads();                             // drains K(0)+V(0)+Q loads

  for (int kc = 0; kc < 36; kc++) {
    // ---- prefetch next iteration's mask values (off the score critical path) ----
    float mnxt[4] = {1.f,1.f,1.f,1.f};
    if (ip && kc < 35) {
      #pragma unroll
      for (int nt=0;nt<4;nt++) mnxt[nt] = mkb[(kc+1)*64 + nt*16 + l16];
    }

    // ---- scores S[16 q][64 keys] = Q K^T (log2 units), K from swizzled LDS ----
    f32x4 sc[4];
    bool keep[4];
    __builtin_amdgcn_s_setprio(1);
    #pragma unroll
    for (int nt=0; nt<4; nt++) {
      int r = nt*16 + l16;
      int rb = r*320;
      int r7 = r&7, r13 = (r>>1)&3;
      f32x4 s = zero;
      #pragma unroll
      for (int ks=0; ks<5; ks++) {
        int g = ks*4 + quad;
        int slot = (ks < 4) ? ((g&8)|((g&7)^r7)) : (16 + (quad^r13));
        bf16x8 bk = *(const bf16x8*)((const char*)Ks + rb + slot*16);
        s = MFMA16(aq[ks], bk, s);
      }
      keep[nt] = true;
      if (ip && mcur[nt] == 0.0f) {
        keep[nt] = false;
        #pragma unroll
        for (int r2=0;r2<4;r2++) s[r2] = -1e30f;
      }
      sc[nt] = s;
    }
    __builtin_amdgcn_s_setprio(0);

    __syncthreads();                           // barA: Ks consumed by all waves

    // ---- issue K(kc+1) DMA into the (now free) single K buffer; drains at barB ----
    if (kc < 35) {
      const char* tile = kbase + (size_t)(kc+1)*20480;
      #pragma unroll
      for (int j=0;j<5;j++) GLD16(tile + ksrc[j], kdst + j*4096);
    }

    // ---- T13 defer-rescale softmax (row = quad*4+r), exp2 domain ----
    float mrow[4];
    #pragma unroll
    for (int r=0;r<4;r++) {
      float mr = fmaxf(fmaxf(sc[0][r], sc[1][r]), fmaxf(sc[2][r], sc[3][r]));
      mrow[r] = row_max16(mr);
    }
    bool fastok = (mrow[0] <= mrun[0]+8.f) & (mrow[1] <= mrun[1]+8.f)
                & (mrow[2] <= mrun[2]+8.f) & (mrow[3] <= mrun[3]+8.f);
    if (!__all(fastok)) {                      // slow path: grow max, rescale o/l
      #pragma unroll
      for (int r=0;r<4;r++) {
        float nm = fmaxf(mrun[r], mrow[r]);
        float alpha = EXP2(fminf(mrun[r] - nm, 0.f));
        mrun[r] = nm;
        lrun[r] *= alpha;
        #pragma unroll
        for (int nt2=0; nt2<10; nt2++) o[nt2][r] *= alpha;
      }
    }
    // p = exp2(sc - mrun) (bounded by 2^8); write Ps immediately (PV operand)
    float p[4][4];
    #pragma unroll
    for (int nt=0;nt<4;nt++)
      #pragma unroll
      for (int r=0;r<4;r++) {
        float e = keep[nt] ? EXP2(sc[nt][r] - mrun[r]) : 0.f;
        p[nt][r] = e;
        Ps[(w*16 + quad*4 + r)*PSTR + nt*16 + l16] = f2b(e);
      }
    #pragma unroll
    for (int r=0;r<4;r++) {
      float rs = (p[0][r]+p[1][r]) + (p[2][r]+p[3][r]);
      rs = row_sum16(rs);
      lrun[r] += rs;
    }

    // ---- O += P V, V B-frags from LDS (XOR-swizzled, bank-floor b128 reads) ----
    __builtin_amdgcn_s_setprio(1);
    #pragma unroll
    for (int kb=0; kb<2; kb++) {
      bf16x8 ap = *(const bf16x8*)&Ps[(w*16 + l16)*PSTR + kb*32 + quad*8];
      #pragma unroll
      for (int nt=0; nt<10; nt++) {
        int d = nt*16 + l16;
        bf16x8 bv = *(const bf16x8*)((const char*)Vs + d*128 + (((kb*4 + quad) ^ (l16 & 7)) << 4));
        o[nt] = MFMA16(ap, bv, o[nt]);
      }
    }
    __builtin_amdgcn_s_setprio(0);

    if (ip) {
      #pragma unroll
      for (int nt=0;nt<4;nt++) mcur[nt] = mnxt[nt];
    }

    __syncthreads();                           // barB: K(kc+1) drained; Vs consumed by all

    // ---- issue V(kc+1) DMA (drains at next iter's barA, covered by QK^T +
    //      cross-block overlap at 3 blocks/CU) ----
    if (kc < 35) {
      const char* vsrc = vbytes + (size_t)(kc+1)*128;   // key-col offset (kc+1)*64 keys *2B
      #pragma unroll
      for (int j5=0;j5<5;j5++) {
        int j = w*5 + j5;
        GLD16(vsrc + (size_t)(j*8 + vrowl)*4608 + vgsw, (char*)Vs + j*1024);
      }
    }
  }

  // ---- epilogue ----
  int b = bh>>3, h = bh&7;
  float scl = 0.f;
  if (ip) {                                   // scalar dtype self-detect (0.5 decodes both ways)
    u16 v0 = ((const u16*)scaleptr)[0];
    int e = (v0 >> 7) & 0xFF;
    scl = (v0 != 0 && e >= 100 && e <= 133) ? b2f(v0) : ((const float*)scaleptr)[0];
  }
  #pragma unroll
  for (int r=0;r<4;r++) {
    int s = q0 + quad*4 + r;
    float linv = (lrun[r] > 0.f) ? 1.0f/lrun[r] : 0.f;
    size_t base = ((size_t)b*2304 + s)*1280 + h*160;
    if (!ip) {
      #pragma unroll
      for (int nt=0;nt<10;nt++) hs[base + nt*16 + l16] = f2b(o[nt][r]*linv);
    } else {
      float f = mig[b*2304 + s]*scl*linv;    // mig uses TRUE b
      #pragma unroll
      for (int nt=0;nt<10;nt++)
        comb[base + nt*16 + l16] = f2b(b2f(hs[base + nt*16 + l16]) + o[nt][r]*f);
    }
  }
}

// ---------------- launch ----------------
extern "C" void kernel_launch(void* const* d_in, const int* in_sizes, int n_in,
                              void* d_out, int out_size, void* d_ws, size_t ws_size,
                              hipStream_t stream)
{
  const float* hid = (const float*)d_in[0];
  const float* Wq  = (const float*)d_in[1];
  const float* Wk  = (const float*)d_in[2];
  const float* Wv  = (const float*)d_in[3];
  const float* Wo  = (const float*)d_in[4];
  const float* bo  = (const float*)d_in[5];
  const float* sks = (const float*)d_in[6];
  const float* svs = (const float*)d_in[7];
  const void*  mid = d_in[8];
  const float* mig = (const float*)d_in[9];
  const void*  scl = d_in[10];

  char* ws = (char*)d_ws;                    // 69.9 MiB total (aliased, stream-ordered)
  float* mk   = (float*)(ws);                // [2][2304]              18432 B
  float* mg   = (float*)(ws + 18432);        // [2][2304]              18432 B
  u32*  mode  = (u32*)(ws + 36864);          // 256 B
  u16*  WT    = (u16*)(ws + 40960);          // 4 x 1280x1280 bf16  13107200 B
  u16*  slotA = (u16*)(ws + 13148160);       // hidB; later sksB (unpadded)       11796480
  u16*  q     = (u16*)(ws + 25534464);       // [16][2304][160] (pre-scaled)      11796480
  u16*  slotB = (u16*)(ws + 37330944);       // k (unpadded); later comb          11796480
  u16*  vt    = (u16*)(ws + 49717248);       // v^T; later vst                    11796480
  u16*  hsB   = (u16*)(ws + 61513728);       // self-attn out bf16                11796480

  maskdet     <<<dim3(1),       256, 0, stream>>>((const u32*)mid, mode);
  maskprep    <<<dim3(18),      256, 0, stream>>>(mid, mig, mk, mg, mode);
  transpose_w <<<dim3(40,40,4), 256, 0, stream>>>(Wq, Wk, Wv, Wo, WT);
  conv        <<<dim3(2880),    256, 0, stream>>>(hid, slotA, 5898240);            // hidB
  gemm128     <<<dim3(36,10,3), 256, 0, stream>>>(slotA, WT, q, slotB, vt, nullptr, nullptr, 0);
  conv        <<<dim3(2880),    256, 0, stream>>>(sks, slotA, 5898240);            // hidB dead -> sksB
  attn        <<<dim3(36,16),   256, 0, stream>>>(q, slotB, vt, nullptr, nullptr, hsB, nullptr, scl, 0);
  transpose_vs<<<dim3(72,5,16), 256, 0, stream>>>(svs, vt);                        // vt dead -> vst
  attn        <<<dim3(36,16),   256, 0, stream>>>(q, slotA, vt, mk, mg, hsB, slotB, scl, 1); // k dead -> comb
  gemm128     <<<dim3(36,10,1), 256, 0, stream>>>(slotB, WT + (size_t)3*1280*1280,
                                                  nullptr, nullptr, nullptr, (float*)d_out, bo, 1);
}

// Round 8
// 464.107 us; speedup vs baseline: 1.1664x; 1.0532x over previous
//
#include <hip/hip_runtime.h>

// Problem: B=2, S=2304, C=1280, NH=8, DH=160, MH=64, SR=48, BH=16
// R13: 495us. R14: 489us - GLD16 gemm swap was ~neutral (lost prefetch overlap,
//      gained DMA staging); attn unchanged 120.5us, conflicts 6.6M->5.3M.
// R15: (a) attn VALU-cut: per-iter budget shows ~70% issue-occupied, VALU 2.9K
//      cy/SIMD dominating. Remove all 32 DPP from the common path: defer-check
//      via __all(lane-local max) [equivalent to row check], l-sum as per-lane
//      partials reduced once in epilogue [alpha row-uniform -> commutes], mask
//      additive -1e30 (mrun init -1e4 keeps all-masked tiles exact). Slow path
//      (rare) still does true DPP row-max rescale.
//      (b) gemm128: DOUBLE-buffered GLD16 (R9 rotated pattern, 1 barrier/iter,
//      DMA covered by MFMA phase). LDS 40KB -> 3 blocks/CU.

typedef unsigned short u16;
typedef unsigned int   u32;
typedef unsigned char  u8;
typedef __attribute__((ext_vector_type(8))) short bf16x8;   // 8 bf16 = 4 VGPRs
typedef __attribute__((ext_vector_type(4))) float f32x4;

#define MFMA16(a,b,c) __builtin_amdgcn_mfma_f32_16x16x32_bf16((a),(b),(c),0,0,0)
#define INVS 0.07905694150420949f                 // 1/sqrt(160)
#define QSCL (0.07905694150420949f * 1.4426950408889634f)   // INVS * log2(e)
#define EXP2(x) __builtin_amdgcn_exp2f(x)
#define PSTR 76                                   // Ps row stride (u16): 38 dw -> write quads on distinct banks
#define MNEG -1.0e30f                             // additive mask for dropped keys

typedef const __attribute__((address_space(1))) void gvoid;
typedef __attribute__((address_space(3))) void lvoid;
#define GLD16(gp, lp) __builtin_amdgcn_global_load_lds((gvoid*)(gp), (lvoid*)(lp), 16, 0, 0)

__device__ __forceinline__ u16 f2b(float f) {            // fp32 -> bf16 RNE
  u32 u = __float_as_uint(f);
  return (u16)((u + 0x7fffu + ((u >> 16) & 1u)) >> 16);
}
__device__ __forceinline__ float b2f(u16 v) { return __uint_as_float(((u32)v) << 16); }

// DPP reduction over a 16-lane row (exactly our l16 domain = one DPP row):
#define DPPF(x, ctrl) __int_as_float(__builtin_amdgcn_update_dpp(0, __float_as_int(x), (ctrl), 0xf, 0xf, true))
__device__ __forceinline__ float row_max16(float x) {
  x = fmaxf(x, DPPF(x, 0xB1));
  x = fmaxf(x, DPPF(x, 0x4E));
  x = fmaxf(x, DPPF(x, 0x141));
  x = fmaxf(x, DPPF(x, 0x140));
  return x;
}
__device__ __forceinline__ float row_sum16(float x) {
  x += DPPF(x, 0xB1);
  x += DPPF(x, 0x4E);
  x += DPPF(x, 0x141);
  x += DPPF(x, 0x140);
  return x;
}

// ---------------- mask-mode detector: 0=i32, 1=u8, 2=bf16, 3=f32 ----------------
__global__ __launch_bounds__(256) void maskdet(const u32* __restrict__ mid, u32* mode)
{
  __shared__ int a0, a1, a2, a3;
  int tid = threadIdx.x;
  if (tid == 0) { a0 = 1; a1 = 1; a2 = 1; a3 = 0; }
  __syncthreads();
  #pragma unroll
  for (int j = 0; j < 4; j++) {
    u32 w = mid[tid*4 + j];                      // first 4 KiB, in-bounds for all dtypes
    if (w > 1u)                      atomicAnd(&a0, 0);  // not i32 bools
    if (w & 0xFEFEFEFEu)             atomicAnd(&a1, 0);  // not u8 bools
    if (w != 0u && w != 0x3F800000u) atomicAnd(&a2, 0);  // not f32 {0,1}
    if ((w & 0xFFFFu) == 0x3F80u)    atomicOr(&a3, 1);   // bf16 1.0 in low half
  }
  __syncthreads();
  if (tid == 0) mode[0] = a0 ? 0u : (a1 ? 1u : (a3 ? 2u : (a2 ? 3u : 0u)));
}

// ---------------- nearest-downsample masks 64x64 -> 48x48 flattened to S ----------------
// mk holds ADDITIVE key-mask offsets: 0.0 (keep) or -1e30 (drop).
__global__ void maskprep(const void* mid, const float* __restrict__ mig_in,
                         float* __restrict__ mk, float* __restrict__ mg, const u32* mode)
{
  int j = blockIdx.x*256 + threadIdx.x;
  if (j >= 2*2304) return;
  u32 md = mode[0];
  int b = j / 2304, s = j % 2304;
  int i = s / 48, jj = s % 48;
  int ih = (i*4)/3, iw = (jj*4)/3;        // arange(48)*64//48
  int src = b*4096 + ih*64 + iw;
  bool on;
  if      (md == 0) on = ((const int*)mid)[src] != 0;
  else if (md == 1) on = ((const u8*)mid)[src]  != 0;
  else if (md == 2) on = ((const u16*)mid)[src] != 0;
  else              on = ((const float*)mid)[src] != 0.0f;
  mk[j] = on ? 0.0f : MNEG;
  mg[j] = mig_in[src];                     // mask_ig is fp32
}

// ---------------- transpose weights: fp32 W[k][n] -> bf16 WT[n][k], 4 matrices --------------
__global__ __launch_bounds__(256) void transpose_w(
    const float* __restrict__ W0, const float* __restrict__ W1,
    const float* __restrict__ W2, const float* __restrict__ W3, u16* __restrict__ WT)
{
  __shared__ u16 t[32][33];
  int z = blockIdx.z;
  const float* s = (z==0)?W0:(z==1)?W1:(z==2)?W2:W3;
  u16* d = WT + (size_t)z*1280*1280;
  int tx = threadIdx.x & 31, ty = (threadIdx.x >> 5) * 4;
  int x = blockIdx.x*32 + tx;          // src col (n)
  int y = blockIdx.y*32 + ty;          // src row (k)
  #pragma unroll
  for (int i=0;i<4;i++) t[ty+i][tx] = f2b(s[(size_t)(y+i)*1280 + x]);
  __syncthreads();
  int x2 = blockIdx.y*32 + tx, y2 = blockIdx.x*32 + ty;
  #pragma unroll
  for (int i=0;i<4;i++) d[(size_t)(y2+i)*1280 + x2] = t[tx][ty+i];   // WT[n][k] = W[k][n]
}

// ---------------- convert fp32 -> bf16 (unpadded) ----------------
__global__ __launch_bounds__(256) void conv(const float* __restrict__ src, u16* __restrict__ dst, int n)
{
  for (int i = blockIdx.x*256 + threadIdx.x; i < n; i += gridDim.x*256)
    dst[i] = f2b(src[i]);
}

// ---------------- transpose store_vs fp32 [16][2304][160] -> bf16 vst[16][160][2304] ---------
__global__ __launch_bounds__(256) void transpose_vs(const float* __restrict__ src, u16* __restrict__ dst)
{
  __shared__ u16 t[32][33];
  int z = blockIdx.z;
  u16* d = dst + (size_t)z*160*2304;
  int tx = threadIdx.x & 31, ty = (threadIdx.x >> 5) * 4;
  int r0 = blockIdx.x*32, c0 = blockIdx.y*32;
  #pragma unroll
  for (int i=0;i<4;i++)
    t[ty+i][tx] = f2b(src[((size_t)z*2304 + r0+ty+i)*160 + c0+tx]);
  __syncthreads();
  #pragma unroll
  for (int i=0;i<4;i++) d[(size_t)(c0+ty+i)*2304 + r0+tx] = t[tx][ty+i]; // d[c][r] = s[r][c]
}

// ---------------- GEMM: 128x128 tile, BK=32, 4 waves (2x2), 16x16x32 MFMA ----------------
// DOUBLE-buffered global_load_lds staging (rotated pipeline, 1 barrier/iter):
//   prologue DMA(t0)->buf0; bar; loop{ DMA(t+1)->buf^1; ds_read+MFMA on buf;
//   bar (drains own DMA; all reads of buf done before t+2 overwrites it) }.
// Per-lane SOURCE offsets place the lane-linear image into padded [128][40] rows.
// kind 0: A=hidB, BT=WT[z]; z=0->q*QSCL, z=1->k [bh][s][160], z=2->v^T [bh][d][s]
// kind 1: A=comb, BT=WoT;   out = A@Wo + bias -> fp32 d_out
__global__ __launch_bounds__(256, 3) void gemm128(
    const u16* __restrict__ A, const u16* __restrict__ BT,
    u16* __restrict__ dq, u16* __restrict__ dk, u16* __restrict__ dvt,
    float* __restrict__ dout, const float* __restrict__ bias, int kind)
{
  __shared__ __align__(16) u16 S[2*2*128*40];  // 2 buffers x (As|Bs), 40960 B
  int tid = threadIdx.x;
  int m0 = blockIdx.x*128, n0 = blockIdx.y*128;
  int z = blockIdx.z;
  const u16* Bt = BT + (size_t)z*1280*1280;
  int w = tid>>6, lane = tid&63, quad = lane>>4, l16 = lane&15;
  int wm = w&1, wn = w>>1;
  // per-thread staging sources: dest granule G = j*256+tid -> LDS byte p=G*16;
  // mat = p/10240 (0=A,1=B); prow = (p%10240)/80; pcol = p%80 (>=64 -> pad).
  const char* ga = (const char*)(A  + (size_t)m0*1280);
  const char* gb = (const char*)(Bt + (size_t)n0*1280);
  const char* sp[5];
  #pragma unroll
  for (int j=0;j<5;j++) {
    int p = j*4096 + tid*16;
    int mat = p / 10240;
    int q2 = p - mat*10240;
    int prow = q2 / 80, pcol = q2 - prow*80;
    int so = prow*2560 + (pcol < 64 ? pcol : 0);
    sp[j] = (mat ? gb : ga) + so;
  }
  char* ldst0 = (char*)S + w*1024;           // wave-uniform dest (HW adds lane*16)
  char* ldst1 = (char*)S + 20480 + w*1024;
  f32x4 zero = {0.f,0.f,0.f,0.f};
  f32x4 acc[4][4];
  #pragma unroll
  for (int a=0;a<4;a++) { acc[a][0]=zero; acc[a][1]=zero; acc[a][2]=zero; acc[a][3]=zero; }
  // prologue: tile 0 -> buf0
  #pragma unroll
  for (int j=0;j<5;j++) GLD16(sp[j], ldst0 + j*4096);
  __syncthreads();
  for (int t = 0; t < 40; t++) {
    int cur = t & 1;
    const u16* Sc = S + cur*10240;           // 10240 u16 = 20480 B per buffer
    if (t < 39) {
      char* nd = cur ? ldst0 : ldst1;
      #pragma unroll
      for (int j=0;j<5;j++) GLD16(sp[j] + (t+1)*64, nd + j*4096);
    }
    bf16x8 af[4], bfr[4];
    #pragma unroll
    for (int mt=0; mt<4; mt++) af[mt]  = *(const bf16x8*)&Sc[(wm*64+mt*16+l16)*40 + quad*8];
    #pragma unroll
    for (int nt=0; nt<4; nt++) bfr[nt] = *(const bf16x8*)&Sc[128*40 + (wn*64+nt*16+l16)*40 + quad*8];
    __builtin_amdgcn_s_setprio(1);
    #pragma unroll
    for (int mt=0; mt<4; mt++)
      #pragma unroll
      for (int nt=0; nt<4; nt++)
        acc[mt][nt] = MFMA16(af[mt], bfr[nt], acc[mt][nt]);
    __builtin_amdgcn_s_setprio(0);
    __syncthreads();                         // drains DMA(t+1); reads of buf cur done
  }
  #pragma unroll
  for (int mt=0; mt<4; mt++) {
    int r0g = m0 + wm*64 + mt*16 + quad*4;          // 4 consecutive rows (reg 0..3)
    #pragma unroll
    for (int nt=0; nt<4; nt++) {
      int col = n0 + wn*64 + nt*16 + l16;
      if (kind == 1) {
        float bi = bias[col];
        #pragma unroll
        for (int r=0;r<4;r++) dout[(size_t)(r0g+r)*1280 + col] = acc[mt][nt][r] + bi;
      } else {
        int h = col/160, d = col%160;
        if (z == 2) {                               // v -> [bh][d][s], s consecutive
          int b = r0g/2304, s0 = r0g%2304;
          size_t base = ((size_t)((b*8+h)*160 + d))*2304 + s0;
          ushort4 pk;
          pk.x = f2b(acc[mt][nt][0]); pk.y = f2b(acc[mt][nt][1]);
          pk.z = f2b(acc[mt][nt][2]); pk.w = f2b(acc[mt][nt][3]);
          *(ushort4*)&dvt[base] = pk;
        } else {
          #pragma unroll
          for (int r=0;r<4;r++) {
            int rg = r0g + r;
            int b = rg/2304, s = rg%2304;
            if (z == 0) dq[((size_t)(b*8+h)*2304 + s)*160 + d] = f2b(acc[mt][nt][r] * QSCL);
            else        dk[((size_t)(b*8+h)*2304 + s)*160 + d] = f2b(acc[mt][nt][r]);
          }
        }
      }
    }
  }
}

// ---------------- Attention (flash-style, online softmax in log2 domain). -------------
// ip=0: self -> hs (bf16). ip=1: keys=sksB, V=vst, additive key mask, combine -> comb.
// SINGLE-buffered K and V, rotated pipeline (2 barriers/iter). Common path has
// ZERO DPP: defer-check via __all(lane-local max <= mrun+8) [== per-row check];
// l-sum kept as per-lane partials (alpha row-uniform -> commutes), reduced once
// in the epilogue. Slow path (rare) does true DPP row-max + rescale.
// mrun init -1e4: masked scores (-1e30) give exp2 -> 0 exactly, even for fully
// masked tiles. K/V staged via GLD16 with XOR-swizzled per-lane sources.
__global__ __launch_bounds__(256, 3) void attn(
    const u16* __restrict__ qg,   // [16][2304][160], pre-scaled by QSCL
    const u16* __restrict__ kg,   // [16][2304][160] unpadded
    const u16* __restrict__ vtg,  // [16][160][2304]
    const float* __restrict__ maskkey, const float* __restrict__ mig,
    u16* __restrict__ hs, u16* __restrict__ comb,
    const void* scaleptr, int ip)
{
  __shared__ __align__(16) u16 Ks[64*160];      // 20480 B, XOR-swizzled granules
  __shared__ __align__(16) u16 Vs[160*64];      // 20480 B, XOR-swizzled granules
  __shared__ __align__(16) u16 Ps[4*16*PSTR];   // 9728 B per-wave P relayout
  // XCD-aware remap: XCD c owns bh {2c, 2c+1} (K+V ~1.5MB/bh fits 4MB L2).
  int id = blockIdx.y*36 + blockIdx.x;
  int xc = id & 7, kq = id >> 3;                 // kq in 0..71
  int bh = 2*xc + (kq >= 36 ? 1 : 0);
  int qt = (kq >= 36) ? kq - 36 : kq;
  int tid = threadIdx.x, w = tid>>6, lane = tid&63, quad = lane>>4, l16 = lane&15;
  int q0 = qt*64 + w*16;                         // wave's 16 queries

  const char* kbase = (const char*)kg + (size_t)bh*2304*320;
  const char* vbytes = (const char*)vtg + ((size_t)bh*160)*2304*2;  // V^T slice base

  // K DMA per-thread swizzled source offsets (dest granule G = j*256+tid):
  u32 ksrc[5];
  #pragma unroll
  for (int j=0;j<5;j++) {
    int G = j*256 + tid;
    int row = G/20, slot = G - row*20;
    int g = (slot < 16) ? ((slot&8)|((slot&7)^(row&7)))
                        : (16 + ((slot&3)^((row>>1)&3)));
    ksrc[j] = row*320 + g*16;
  }
  char* kdst = (char*)Ks + w*1024;               // wave-uniform dest (HW adds lane*16)

  // V DMA lane geometry: instr j covers d-rows [j*8, j*8+8), 8 lanes per row.
  int vrowl = lane>>3;                          // local d row 0..7
  int vgsw  = ((lane&7) ^ vrowl) << 4;          // swizzled source byte offset

  // ---- prologue: issue K(0) + V(0) DMA (both drained by the pre-loop barrier) ----
  {
    #pragma unroll
    for (int j=0;j<5;j++) GLD16(kbase + ksrc[j], kdst + j*4096);
    #pragma unroll
    for (int j5=0;j5<5;j5++) {
      int j = w*5 + j5;
      GLD16(vbytes + (size_t)(j*8 + vrowl)*4608 + vgsw, (char*)Vs + j*1024);
    }
  }

  bf16x8 aq[5];                                // Q frags: A[m=l16][k=quad*8+j], 5 ksteps
  {
    const u16* qrow = qg + ((size_t)bh*2304 + q0 + l16)*160 + quad*8;
    #pragma unroll
    for (int ks=0; ks<5; ks++) aq[ks] = *(const bf16x8*)(qrow + ks*32);
  }
  f32x4 zero = {0.f,0.f,0.f,0.f};
  f32x4 o[10];
  #pragma unroll
  for (int i=0;i<10;i++) o[i] = zero;
  float mrun[4] = {-1e4f,-1e4f,-1e4f,-1e4f};   // low enough that exp2(-1e30-m)=0
  float lsum[4] = {0.f,0.f,0.f,0.f};           // PER-LANE partial sums (reduced in epilogue)

  const float* mkb = ip ? (maskkey + (bh & 1)*2304) : nullptr;
  float mcur[4] = {0.f,0.f,0.f,0.f};           // additive offsets
  if (ip) {
    #pragma unroll
    for (int nt=0;nt<4;nt++) mcur[nt] = mkb[nt*16 + l16];
  }

  __syncthreads();                             // drains K(0)+V(0)+Q loads

  for (int kc = 0; kc < 36; kc++) {
    // ---- prefetch next iteration's mask values (off the score critical path) ----
    float mnxt[4] = {0.f,0.f,0.f,0.f};
    if (ip && kc < 35) {
      #pragma unroll
      for (int nt=0;nt<4;nt++) mnxt[nt] = mkb[(kc+1)*64 + nt*16 + l16];
    }

    // ---- scores S[16 q][64 keys] = Q K^T (log2 units), K from swizzled LDS ----
    f32x4 sc[4];
    __builtin_amdgcn_s_setprio(1);
    #pragma unroll
    for (int nt=0; nt<4; nt++) {
      int r = nt*16 + l16;
      int rb = r*320;
      int r7 = r&7, r13 = (r>>1)&3;
      f32x4 s = zero;
      #pragma unroll
      for (int ks=0; ks<5; ks++) {
        int g = ks*4 + quad;
        int slot = (ks < 4) ? ((g&8)|((g&7)^r7)) : (16 + (quad^r13));
        bf16x8 bk = *(const bf16x8*)((const char*)Ks + rb + slot*16);
        s = MFMA16(aq[ks], bk, s);
      }
      if (ip) {
        #pragma unroll
        for (int r2=0;r2<4;r2++) s[r2] += mcur[nt];   // 0 or -1e30
      }
      sc[nt] = s;
    }
    __builtin_amdgcn_s_setprio(0);

    __syncthreads();                           // barA: Ks consumed by all waves

    // ---- issue K(kc+1) DMA into the (now free) single K buffer; drains at barB ----
    if (kc < 35) {
      const char* tile = kbase + (size_t)(kc+1)*20480;
      #pragma unroll
      for (int j=0;j<5;j++) GLD16(tile + ksrc[j], kdst + j*4096);
    }

    // ---- T13 defer-rescale softmax, ZERO-DPP common path ----
    float lmax[4];
    #pragma unroll
    for (int r=0;r<4;r++)
      lmax[r] = fmaxf(fmaxf(sc[0][r], sc[1][r]), fmaxf(sc[2][r], sc[3][r]));
    bool fastok = (lmax[0] <= mrun[0]+8.f) & (lmax[1] <= mrun[1]+8.f)
                & (lmax[2] <= mrun[2]+8.f) & (lmax[3] <= mrun[3]+8.f);
    if (!__all(fastok)) {                      // slow path: true row max, rescale o/l
      #pragma unroll
      for (int r=0;r<4;r++) {
        float mr = row_max16(lmax[r]);         // row-uniform
        float nm = fmaxf(mrun[r], mr);
        float alpha = EXP2(fminf(mrun[r] - nm, 0.f));   // row-uniform
        mrun[r] = nm;
        lsum[r] *= alpha;                      // partial scales consistently
        #pragma unroll
        for (int nt2=0; nt2<10; nt2++) o[nt2][r] *= alpha;
      }
    }
    // p = exp2(sc - mrun) (bounded by 2^8; masked -> 0); Ps written immediately
    float p[4][4];
    #pragma unroll
    for (int nt=0;nt<4;nt++)
      #pragma unroll
      for (int r=0;r<4;r++) {
        float e = EXP2(sc[nt][r] - mrun[r]);
        p[nt][r] = e;
        Ps[(w*16 + quad*4 + r)*PSTR + nt*16 + l16] = f2b(e);
      }
    #pragma unroll
    for (int r=0;r<4;r++)
      lsum[r] += (p[0][r]+p[1][r]) + (p[2][r]+p[3][r]);   // per-lane partial, no DPP

    // ---- O += P V, V B-frags from LDS (XOR-swizzled, bank-floor b128 reads) ----
    __builtin_amdgcn_s_setprio(1);
    #pragma unroll
    for (int kb=0; kb<2; kb++) {
      bf16x8 ap = *(const bf16x8*)&Ps[(w*16 + l16)*PSTR + kb*32 + quad*8];
      #pragma unroll
      for (int nt=0; nt<10; nt++) {
        int d = nt*16 + l16;
        bf16x8 bv = *(const bf16x8*)((const char*)Vs + d*128 + (((kb*4 + quad) ^ (l16 & 7)) << 4));
        o[nt] = MFMA16(ap, bv, o[nt]);
      }
    }
    __builtin_amdgcn_s_setprio(0);

    if (ip) {
      #pragma unroll
      for (int nt=0;nt<4;nt++) mcur[nt] = mnxt[nt];
    }

    __syncthreads();                           // barB: K(kc+1) drained; Vs consumed by all

    // ---- issue V(kc+1) DMA (drains at next iter's barA, covered by QK^T +
    //      cross-block overlap at 3 blocks/CU) ----
    if (kc < 35) {
      const char* vsrc = vbytes + (size_t)(kc+1)*128;   // key-col offset (kc+1)*64 keys *2B
      #pragma unroll
      for (int j5=0;j5<5;j5++) {
        int j = w*5 + j5;
        GLD16(vsrc + (size_t)(j*8 + vrowl)*4608 + vgsw, (char*)Vs + j*1024);
      }
    }
  }

  // ---- epilogue: one row-reduction of the deferred l partials ----
  float lrun[4];
  #pragma unroll
  for (int r=0;r<4;r++) lrun[r] = row_sum16(lsum[r]);
  int b = bh>>3, h = bh&7;
  float scl = 0.f;
  if (ip) {                                   // scalar dtype self-detect (0.5 decodes both ways)
    u16 v0 = ((const u16*)scaleptr)[0];
    int e = (v0 >> 7) & 0xFF;
    scl = (v0 != 0 && e >= 100 && e <= 133) ? b2f(v0) : ((const float*)scaleptr)[0];
  }
  #pragma unroll
  for (int r=0;r<4;r++) {
    int s = q0 + quad*4 + r;
    float linv = (lrun[r] > 0.f) ? 1.0f/lrun[r] : 0.f;
    size_t base = ((size_t)b*2304 + s)*1280 + h*160;
    if (!ip) {
      #pragma unroll
      for (int nt=0;nt<10;nt++) hs[base + nt*16 + l16] = f2b(o[nt][r]*linv);
    } else {
      float f = mig[b*2304 + s]*scl*linv;    // mig uses TRUE b
      #pragma unroll
      for (int nt=0;nt<10;nt++)
        comb[base + nt*16 + l16] = f2b(b2f(hs[base + nt*16 + l16]) + o[nt][r]*f);
    }
  }
}

// ---------------- launch ----------------
extern "C" void kernel_launch(void* const* d_in, const int* in_sizes, int n_in,
                              void* d_out, int out_size, void* d_ws, size_t ws_size,
                              hipStream_t stream)
{
  const float* hid = (const float*)d_in[0];
  const float* Wq  = (const float*)d_in[1];
  const float* Wk  = (const float*)d_in[2];
  const float* Wv  = (const float*)d_in[3];
  const float* Wo  = (const float*)d_in[4];
  const float* bo  = (const float*)d_in[5];
  const float* sks = (const float*)d_in[6];
  const float* svs = (const float*)d_in[7];
  const void*  mid = d_in[8];
  const float* mig = (const float*)d_in[9];
  const void*  scl = d_in[10];

  char* ws = (char*)d_ws;                    // 69.9 MiB total (aliased, stream-ordered)
  float* mk   = (float*)(ws);                // [2][2304] additive offsets  18432 B
  float* mg   = (float*)(ws + 18432);        // [2][2304]              18432 B
  u32*  mode  = (u32*)(ws + 36864);          // 256 B
  u16*  WT    = (u16*)(ws + 40960);          // 4 x 1280x1280 bf16  13107200 B
  u16*  slotA = (u16*)(ws + 13148160);       // hidB; later sksB (unpadded)       11796480
  u16*  q     = (u16*)(ws + 25534464);       // [16][2304][160] (pre-scaled)      11796480
  u16*  slotB = (u16*)(ws + 37330944);       // k (unpadded); later comb          11796480
  u16*  vt    = (u16*)(ws + 49717248);       // v^T; later vst                    11796480
  u16*  hsB   = (u16*)(ws + 61513728);       // self-attn out bf16                11796480

  maskdet     <<<dim3(1),       256, 0, stream>>>((const u32*)mid, mode);
  maskprep    <<<dim3(18),      256, 0, stream>>>(mid, mig, mk, mg, mode);
  transpose_w <<<dim3(40,40,4), 256, 0, stream>>>(Wq, Wk, Wv, Wo, WT);
  conv        <<<dim3(2880),    256, 0, stream>>>(hid, slotA, 5898240);            // hidB
  gemm128     <<<dim3(36,10,3), 256, 0, stream>>>(slotA, WT, q, slotB, vt, nullptr, nullptr, 0);
  conv        <<<dim3(2880),    256, 0, stream>>>(sks, slotA, 5898240);            // hidB dead -> sksB
  attn        <<<dim3(36,16),   256, 0, stream>>>(q, slotB, vt, nullptr, nullptr, hsB, nullptr, scl, 0);
  transpose_vs<<<dim3(72,5,16), 256, 0, stream>>>(svs, vt);                        // vt dead -> vst
  attn        <<<dim3(36,16),   256, 0, stream>>>(q, slotA, vt, mk, mg, hsB, slotB, scl, 1); // k dead -> comb
  gemm128     <<<dim3(36,10,1), 256, 0, stream>>>(slotB, WT + (size_t)3*1280*1280,
                                                  nullptr, nullptr, nullptr, (float*)d_out, bo, 1);
}

// Round 9
// 461.155 us; speedup vs baseline: 1.1739x; 1.0064x over previous
//
#include <hip/hip_runtime.h>

// Problem: B=2, S=2304, C=1280, NH=8, DH=160, MH=64, SR=48, BH=16
// R15: 464us. attn 2x113.3 (MfmaUtil 20.3, VALU 30.4) - zero-DPP softmax +
//      dbuf GLD16 gemm. Non-attn = 237us, ~75us above component model.
// R16: (a) q,k stored in NATURAL gemm layout [b][s][1280]: z0/z1 epilogue
//      becomes coalesced row-writes (no div/mod 160, no 320B-stride scatter).
//      attn takes a runtime K row-stride (2560B for q/k natural, 320B for sks)
//      - same instruction count, per-lane DMA sources absorb the layout.
//      (b) dispatch count 10 -> 7: maskdet merged into maskprep (per-block
//      mode re-detect), conv(hid) merged into transpose_w (z==4 slice),
//      conv(sks) merged into transpose_vs (z==16 slice).
//      (c) gemm __launch_bounds__(256,4): LDS 4x40960 = exactly 160KB,
//      1080 blocks -> 1.05 rounds instead of 1.41 (tail shrink).

typedef unsigned short u16;
typedef unsigned int   u32;
typedef unsigned char  u8;
typedef __attribute__((ext_vector_type(8))) short bf16x8;   // 8 bf16 = 4 VGPRs
typedef __attribute__((ext_vector_type(4))) float f32x4;

#define MFMA16(a,b,c) __builtin_amdgcn_mfma_f32_16x16x32_bf16((a),(b),(c),0,0,0)
#define INVS 0.07905694150420949f                 // 1/sqrt(160)
#define QSCL (0.07905694150420949f * 1.4426950408889634f)   // INVS * log2(e)
#define EXP2(x) __builtin_amdgcn_exp2f(x)
#define PSTR 76                                   // Ps row stride (u16): 38 dw -> write quads on distinct banks
#define MNEG -1.0e30f                             // additive mask for dropped keys

typedef const __attribute__((address_space(1))) void gvoid;
typedef __attribute__((address_space(3))) void lvoid;
#define GLD16(gp, lp) __builtin_amdgcn_global_load_lds((gvoid*)(gp), (lvoid*)(lp), 16, 0, 0)

__device__ __forceinline__ u16 f2b(float f) {            // fp32 -> bf16 RNE
  u32 u = __float_as_uint(f);
  return (u16)((u + 0x7fffu + ((u >> 16) & 1u)) >> 16);
}
__device__ __forceinline__ float b2f(u16 v) { return __uint_as_float(((u32)v) << 16); }

// DPP reduction over a 16-lane row (exactly our l16 domain = one DPP row):
#define DPPF(x, ctrl) __int_as_float(__builtin_amdgcn_update_dpp(0, __float_as_int(x), (ctrl), 0xf, 0xf, true))
__device__ __forceinline__ float row_max16(float x) {
  x = fmaxf(x, DPPF(x, 0xB1));
  x = fmaxf(x, DPPF(x, 0x4E));
  x = fmaxf(x, DPPF(x, 0x141));
  x = fmaxf(x, DPPF(x, 0x140));
  return x;
}
__device__ __forceinline__ float row_sum16(float x) {
  x += DPPF(x, 0xB1);
  x += DPPF(x, 0x4E);
  x += DPPF(x, 0x141);
  x += DPPF(x, 0x140);
  return x;
}

// ---------------- maskprep: per-block mode detect + nearest-downsample 64x64 -> 48x48 ------
// mk holds ADDITIVE key-mask offsets: 0.0 (keep) or -1e30 (drop).
__global__ __launch_bounds__(256) void maskprep(const void* mid, const float* __restrict__ mig_in,
                                                float* __restrict__ mk, float* __restrict__ mg)
{
  __shared__ int a0, a1, a2, a3;
  int tid = threadIdx.x;
  if (tid == 0) { a0 = 1; a1 = 1; a2 = 1; a3 = 0; }
  __syncthreads();
  #pragma unroll
  for (int jj = 0; jj < 4; jj++) {
    u32 w = ((const u32*)mid)[tid*4 + jj];        // first 4 KiB, in-bounds for all dtypes
    if (w > 1u)                      atomicAnd(&a0, 0);  // not i32 bools
    if (w & 0xFEFEFEFEu)             atomicAnd(&a1, 0);  // not u8 bools
    if (w != 0u && w != 0x3F800000u) atomicAnd(&a2, 0);  // not f32 {0,1}
    if ((w & 0xFFFFu) == 0x3F80u)    atomicOr(&a3, 1);   // bf16 1.0 in low half
  }
  __syncthreads();
  u32 md = a0 ? 0u : (a1 ? 1u : (a3 ? 2u : (a2 ? 3u : 0u)));

  int j = blockIdx.x*256 + tid;
  if (j >= 2*2304) return;
  int b = j / 2304, s = j % 2304;
  int i = s / 48, jj = s % 48;
  int ih = (i*4)/3, iw = (jj*4)/3;        // arange(48)*64//48
  int src = b*4096 + ih*64 + iw;
  bool on;
  if      (md == 0) on = ((const int*)mid)[src] != 0;
  else if (md == 1) on = ((const u8*)mid)[src]  != 0;
  else if (md == 2) on = ((const u16*)mid)[src] != 0;
  else              on = ((const float*)mid)[src] != 0.0f;
  mk[j] = on ? 0.0f : MNEG;
  mg[j] = mig_in[src];                     // mask_ig is fp32
}

// ---------------- prep_w: transpose 4 weights (z<4) + conv hid fp32->bf16 (z==4) ------------
__global__ __launch_bounds__(256) void prep_w(
    const float* __restrict__ W0, const float* __restrict__ W1,
    const float* __restrict__ W2, const float* __restrict__ W3, u16* __restrict__ WT,
    const float* __restrict__ hid, u16* __restrict__ hidB)
{
  int z = blockIdx.z;
  if (z == 4) {                                    // conv slice: 1600 blocks grid-stride
    int lb = blockIdx.x + 40*blockIdx.y;
    for (int i = lb*256 + threadIdx.x; i < 5898240; i += 1600*256)
      hidB[i] = f2b(hid[i]);
    return;
  }
  __shared__ u16 t[32][33];
  const float* s = (z==0)?W0:(z==1)?W1:(z==2)?W2:W3;
  u16* d = WT + (size_t)z*1280*1280;
  int tx = threadIdx.x & 31, ty = (threadIdx.x >> 5) * 4;
  int x = blockIdx.x*32 + tx;          // src col (n)
  int y = blockIdx.y*32 + ty;          // src row (k)
  #pragma unroll
  for (int i=0;i<4;i++) t[ty+i][tx] = f2b(s[(size_t)(y+i)*1280 + x]);
  __syncthreads();
  int x2 = blockIdx.y*32 + tx, y2 = blockIdx.x*32 + ty;
  #pragma unroll
  for (int i=0;i<4;i++) d[(size_t)(y2+i)*1280 + x2] = t[tx][ty+i];   // WT[n][k] = W[k][n]
}

// ---------------- prep_vs: transpose store_vs (z<16) + conv sks fp32->bf16 (z==16) ----------
// vst[16][160][2304]; sksB stays [16][2304][160] bf16.
__global__ __launch_bounds__(256) void prep_vs(
    const float* __restrict__ svs, u16* __restrict__ vst,
    const float* __restrict__ sks, u16* __restrict__ sksB)
{
  int z = blockIdx.z;
  if (z == 16) {                                   // conv slice: 360 blocks grid-stride
    int lb = blockIdx.x + 72*blockIdx.y;
    for (int i = lb*256 + threadIdx.x; i < 5898240; i += 360*256)
      sksB[i] = f2b(sks[i]);
    return;
  }
  __shared__ u16 t[32][33];
  u16* d = vst + (size_t)z*160*2304;
  int tx = threadIdx.x & 31, ty = (threadIdx.x >> 5) * 4;
  int r0 = blockIdx.x*32, c0 = blockIdx.y*32;
  #pragma unroll
  for (int i=0;i<4;i++)
    t[ty+i][tx] = f2b(svs[((size_t)z*2304 + r0+ty+i)*160 + c0+tx]);
  __syncthreads();
  #pragma unroll
  for (int i=0;i<4;i++) d[(size_t)(c0+ty+i)*2304 + r0+tx] = t[tx][ty+i]; // d[c][r] = s[r][c]
}

// ---------------- GEMM: 128x128 tile, BK=32, 4 waves (2x2), 16x16x32 MFMA ----------------
// DOUBLE-buffered global_load_lds staging (rotated pipeline, 1 barrier/iter).
// kind 0: A=hidB, BT=WT[z]; z=0 -> q*QSCL NATURAL [b][s][1280] (coalesced rows),
//         z=1 -> k NATURAL [b][s][1280], z=2 -> v^T [bh][d][s].
// kind 1: A=comb, BT=WoT; out = A@Wo + bias -> fp32 d_out.
__global__ __launch_bounds__(256, 4) void gemm128(
    const u16* __restrict__ A, const u16* __restrict__ BT,
    u16* __restrict__ dq, u16* __restrict__ dk, u16* __restrict__ dvt,
    float* __restrict__ dout, const float* __restrict__ bias, int kind)
{
  __shared__ __align__(16) u16 S[2*2*128*40];  // 2 buffers x (As|Bs), 40960 B
  int tid = threadIdx.x;
  int m0 = blockIdx.x*128, n0 = blockIdx.y*128;
  int z = blockIdx.z;
  const u16* Bt = BT + (size_t)z*1280*1280;
  int w = tid>>6, lane = tid&63, quad = lane>>4, l16 = lane&15;
  int wm = w&1, wn = w>>1;
  // per-thread staging sources: dest granule G = j*256+tid -> LDS byte p=G*16;
  // mat = p/10240 (0=A,1=B); prow = (p%10240)/80; pcol = p%80 (>=64 -> pad).
  const char* ga = (const char*)(A  + (size_t)m0*1280);
  const char* gb = (const char*)(Bt + (size_t)n0*1280);
  const char* sp[5];
  #pragma unroll
  for (int j=0;j<5;j++) {
    int p = j*4096 + tid*16;
    int mat = p / 10240;
    int q2 = p - mat*10240;
    int prow = q2 / 80, pcol = q2 - prow*80;
    int so = prow*2560 + (pcol < 64 ? pcol : 0);
    sp[j] = (mat ? gb : ga) + so;
  }
  char* ldst0 = (char*)S + w*1024;           // wave-uniform dest (HW adds lane*16)
  char* ldst1 = (char*)S + 20480 + w*1024;
  f32x4 zero = {0.f,0.f,0.f,0.f};
  f32x4 acc[4][4];
  #pragma unroll
  for (int a=0;a<4;a++) { acc[a][0]=zero; acc[a][1]=zero; acc[a][2]=zero; acc[a][3]=zero; }
  // prologue: tile 0 -> buf0
  #pragma unroll
  for (int j=0;j<5;j++) GLD16(sp[j], ldst0 + j*4096);
  __syncthreads();
  for (int t = 0; t < 40; t++) {
    int cur = t & 1;
    const u16* Sc = S + cur*10240;           // 10240 u16 = 20480 B per buffer
    if (t < 39) {
      char* nd = cur ? ldst0 : ldst1;
      #pragma unroll
      for (int j=0;j<5;j++) GLD16(sp[j] + (t+1)*64, nd + j*4096);
    }
    bf16x8 af[4], bfr[4];
    #pragma unroll
    for (int mt=0; mt<4; mt++) af[mt]  = *(const bf16x8*)&Sc[(wm*64+mt*16+l16)*40 + quad*8];
    #pragma unroll
    for (int nt=0; nt<4; nt++) bfr[nt] = *(const bf16x8*)&Sc[128*40 + (wn*64+nt*16+l16)*40 + quad*8];
    __builtin_amdgcn_s_setprio(1);
    #pragma unroll
    for (int mt=0; mt<4; mt++)
      #pragma unroll
      for (int nt=0; nt<4; nt++)
        acc[mt][nt] = MFMA16(af[mt], bfr[nt], acc[mt][nt]);
    __builtin_amdgcn_s_setprio(0);
    __syncthreads();                         // drains DMA(t+1); reads of buf cur done
  }
  #pragma unroll
  for (int mt=0; mt<4; mt++) {
    int r0g = m0 + wm*64 + mt*16 + quad*4;          // 4 consecutive rows (reg 0..3)
    #pragma unroll
    for (int nt=0; nt<4; nt++) {
      int col = n0 + wn*64 + nt*16 + l16;
      if (kind == 1) {
        float bi = bias[col];
        #pragma unroll
        for (int r=0;r<4;r++) dout[(size_t)(r0g+r)*1280 + col] = acc[mt][nt][r] + bi;
      } else if (z == 2) {                          // v -> [bh][d][s], s consecutive
        int h = col/160, d = col%160;
        int b = r0g/2304, s0 = r0g%2304;
        size_t base = ((size_t)((b*8+h)*160 + d))*2304 + s0;
        ushort4 pk;
        pk.x = f2b(acc[mt][nt][0]); pk.y = f2b(acc[mt][nt][1]);
        pk.z = f2b(acc[mt][nt][2]); pk.w = f2b(acc[mt][nt][3]);
        *(ushort4*)&dvt[base] = pk;
      } else {                                      // q/k NATURAL layout: coalesced rows
        #pragma unroll
        for (int r=0;r<4;r++) {
          int rg = r0g + r;
          if (z == 0) dq[(size_t)rg*1280 + col] = f2b(acc[mt][nt][r] * QSCL);
          else        dk[(size_t)rg*1280 + col] = f2b(acc[mt][nt][r]);
        }
      }
    }
  }
}

// ---------------- Attention (flash-style, online softmax in log2 domain). -------------
// ip=0: self -> hs (bf16); K = q/k NATURAL [b][s][1280] (row stride 2560B, col h*160).
// ip=1: keys=sksB [16][2304][160] (row stride 320B), V=vst, additive key mask,
//       combine -> comb. SINGLE-buffered K and V, rotated pipeline (2 barriers/iter).
// Zero-DPP common path (R15). K/V staged via GLD16 with XOR-swizzled per-lane
// sources; K row stride is a runtime param folded into the source offsets.
__global__ __launch_bounds__(256, 3) void attn(
    const u16* __restrict__ qg,   // NATURAL [2][2304][1280], pre-scaled by QSCL
    const u16* __restrict__ kg,   // ip=0: [2][2304][1280]; ip=1: [16][2304][160]
    const u16* __restrict__ vtg,  // [16][160][2304]
    const float* __restrict__ maskkey, const float* __restrict__ mig,
    u16* __restrict__ hs, u16* __restrict__ comb,
    const void* scaleptr, int ip)
{
  __shared__ __align__(16) u16 Ks[64*160];      // 20480 B, XOR-swizzled granules
  __shared__ __align__(16) u16 Vs[160*64];      // 20480 B, XOR-swizzled granules
  __shared__ __align__(16) u16 Ps[4*16*PSTR];   // 9728 B per-wave P relayout
  // XCD-aware remap: XCD c owns bh {2c, 2c+1} (K+V ~1.5MB/bh fits 4MB L2).
  int id = blockIdx.y*36 + blockIdx.x;
  int xc = id & 7, kq = id >> 3;                 // kq in 0..71
  int bh = 2*xc + (kq >= 36 ? 1 : 0);
  int qt = (kq >= 36) ? kq - 36 : kq;
  int tid = threadIdx.x, w = tid>>6, lane = tid&63, quad = lane>>4, l16 = lane&15;
  int q0 = qt*64 + w*16;                         // wave's 16 queries
  int b = bh>>3, h = bh&7;

  // K layout: natural (ip=0) vs per-head (ip=1); row stride + base differ.
  const char* kbase; u32 kstr;
  if (!ip) { kbase = (const char*)kg + ((size_t)b*2304*1280 + (size_t)h*160)*2; kstr = 2560; }
  else     { kbase = (const char*)kg + (size_t)bh*2304*320;                     kstr = 320;  }
  u32 tilestep = kstr*64;
  const char* vbytes = (const char*)vtg + ((size_t)bh*160)*2304*2;  // V^T slice base

  // K DMA per-thread swizzled source offsets (dest granule G = j*256+tid):
  u32 ksrc[5];
  #pragma unroll
  for (int j=0;j<5;j++) {
    int G = j*256 + tid;
    int row = G/20, slot = G - row*20;
    int g = (slot < 16) ? ((slot&8)|((slot&7)^(row&7)))
                        : (16 + ((slot&3)^((row>>1)&3)));
    ksrc[j] = (u32)row*kstr + g*16;
  }
  char* kdst = (char*)Ks + w*1024;               // wave-uniform dest (HW adds lane*16)

  // V DMA lane geometry: instr j covers d-rows [j*8, j*8+8), 8 lanes per row.
  int vrowl = lane>>3;                          // local d row 0..7
  int vgsw  = ((lane&7) ^ vrowl) << 4;          // swizzled source byte offset

  // ---- prologue: issue K(0) + V(0) DMA (both drained by the pre-loop barrier) ----
  {
    #pragma unroll
    for (int j=0;j<5;j++) GLD16(kbase + ksrc[j], kdst + j*4096);
    #pragma unroll
    for (int j5=0;j5<5;j5++) {
      int j = w*5 + j5;
      GLD16(vbytes + (size_t)(j*8 + vrowl)*4608 + vgsw, (char*)Vs + j*1024);
    }
  }

  bf16x8 aq[5];                                // Q frags: A[m=l16][k=quad*8+j], 5 ksteps
  {
    const u16* qrow = qg + ((size_t)(b*2304 + q0 + l16))*1280 + h*160 + quad*8;
    #pragma unroll
    for (int ks=0; ks<5; ks++) aq[ks] = *(const bf16x8*)(qrow + ks*32);
  }
  f32x4 zero = {0.f,0.f,0.f,0.f};
  f32x4 o[10];
  #pragma unroll
  for (int i=0;i<10;i++) o[i] = zero;
  float mrun[4] = {-1e4f,-1e4f,-1e4f,-1e4f};   // low enough that exp2(-1e30-m)=0
  float lsum[4] = {0.f,0.f,0.f,0.f};           // PER-LANE partial sums (reduced in epilogue)

  const float* mkb = ip ? (maskkey + (bh & 1)*2304) : nullptr;
  float mcur[4] = {0.f,0.f,0.f,0.f};           // additive offsets
  if (ip) {
    #pragma unroll
    for (int nt=0;nt<4;nt++) mcur[nt] = mkb[nt*16 + l16];
  }

  __syncthreads();                             // drains K(0)+V(0)+Q loads

  for (int kc = 0; kc < 36; kc++) {
    // ---- prefetch next iteration's mask values (off the score critical path) ----
    float mnxt[4] = {0.f,0.f,0.f,0.f};
    if (ip && kc < 35) {
      #pragma unroll
      for (int nt=0;nt<4;nt++) mnxt[nt] = mkb[(kc+1)*64 + nt*16 + l16];
    }

    // ---- scores S[16 q][64 keys] = Q K^T (log2 units), K from swizzled LDS ----
    f32x4 sc[4];
    __builtin_amdgcn_s_setprio(1);
    #pragma unroll
    for (int nt=0; nt<4; nt++) {
      int r = nt*16 + l16;
      int rb = r*320;
      int r7 = r&7, r13 = (r>>1)&3;
      f32x4 s = zero;
      #pragma unroll
      for (int ks=0; ks<5; ks++) {
        int g = ks*4 + quad;
        int slot = (ks < 4) ? ((g&8)|((g&7)^r7)) : (16 + (quad^r13));
        bf16x8 bk = *(const bf16x8*)((const char*)Ks + rb + slot*16);
        s = MFMA16(aq[ks], bk, s);
      }
      if (ip) {
        #pragma unroll
        for (int r2=0;r2<4;r2++) s[r2] += mcur[nt];   // 0 or -1e30
      }
      sc[nt] = s;
    }
    __builtin_amdgcn_s_setprio(0);

    __syncthreads();                           // barA: Ks consumed by all waves

    // ---- issue K(kc+1) DMA into the (now free) single K buffer; drains at barB ----
    if (kc < 35) {
      const char* tile = kbase + (size_t)(kc+1)*tilestep;
      #pragma unroll
      for (int j=0;j<5;j++) GLD16(tile + ksrc[j], kdst + j*4096);
    }

    // ---- T13 defer-rescale softmax, ZERO-DPP common path ----
    float lmax[4];
    #pragma unroll
    for (int r=0;r<4;r++)
      lmax[r] = fmaxf(fmaxf(sc[0][r], sc[1][r]), fmaxf(sc[2][r], sc[3][r]));
    bool fastok = (lmax[0] <= mrun[0]+8.f) & (lmax[1] <= mrun[1]+8.f)
                & (lmax[2] <= mrun[2]+8.f) & (lmax[3] <= mrun[3]+8.f);
    if (!__all(fastok)) {                      // slow path: true row max, rescale o/l
      #pragma unroll
      for (int r=0;r<4;r++) {
        float mr = row_max16(lmax[r]);         // row-uniform
        float nm = fmaxf(mrun[r], mr);
        float alpha = EXP2(fminf(mrun[r] - nm, 0.f));   // row-uniform
        mrun[r] = nm;
        lsum[r] *= alpha;                      // partial scales consistently
        #pragma unroll
        for (int nt2=0; nt2<10; nt2++) o[nt2][r] *= alpha;
      }
    }
    // p = exp2(sc - mrun) (bounded by 2^8; masked -> 0); Ps written immediately
    float p[4][4];
    #pragma unroll
    for (int nt=0;nt<4;nt++)
      #pragma unroll
      for (int r=0;r<4;r++) {
        float e = EXP2(sc[nt][r] - mrun[r]);
        p[nt][r] = e;
        Ps[(w*16 + quad*4 + r)*PSTR + nt*16 + l16] = f2b(e);
      }
    #pragma unroll
    for (int r=0;r<4;r++)
      lsum[r] += (p[0][r]+p[1][r]) + (p[2][r]+p[3][r]);   // per-lane partial, no DPP

    // ---- O += P V, V B-frags from LDS (XOR-swizzled, bank-floor b128 reads) ----
    __builtin_amdgcn_s_setprio(1);
    #pragma unroll
    for (int kb=0; kb<2; kb++) {
      bf16x8 ap = *(const bf16x8*)&Ps[(w*16 + l16)*PSTR + kb*32 + quad*8];
      #pragma unroll
      for (int nt=0; nt<10; nt++) {
        int d = nt*16 + l16;
        bf16x8 bv = *(const bf16x8*)((const char*)Vs + d*128 + (((kb*4 + quad) ^ (l16 & 7)) << 4));
        o[nt] = MFMA16(ap, bv, o[nt]);
      }
    }
    __builtin_amdgcn_s_setprio(0);

    if (ip) {
      #pragma unroll
      for (int nt=0;nt<4;nt++) mcur[nt] = mnxt[nt];
    }

    __syncthreads();                           // barB: K(kc+1) drained; Vs consumed by all

    // ---- issue V(kc+1) DMA (drains at next iter's barA, covered by QK^T +
    //      cross-block overlap at 3 blocks/CU) ----
    if (kc < 35) {
      const char* vsrc = vbytes + (size_t)(kc+1)*128;   // key-col offset (kc+1)*64 keys *2B
      #pragma unroll
      for (int j5=0;j5<5;j5++) {
        int j = w*5 + j5;
        GLD16(vsrc + (size_t)(j*8 + vrowl)*4608 + vgsw, (char*)Vs + j*1024);
      }
    }
  }

  // ---- epilogue: one row-reduction of the deferred l partials ----
  float lrun[4];
  #pragma unroll
  for (int r=0;r<4;r++) lrun[r] = row_sum16(lsum[r]);
  float scl = 0.f;
  if (ip) {                                   // scalar dtype self-detect (0.5 decodes both ways)
    u16 v0 = ((const u16*)scaleptr)[0];
    int e = (v0 >> 7) & 0xFF;
    scl = (v0 != 0 && e >= 100 && e <= 133) ? b2f(v0) : ((const float*)scaleptr)[0];
  }
  #pragma unroll
  for (int r=0;r<4;r++) {
    int s = q0 + quad*4 + r;
    float linv = (lrun[r] > 0.f) ? 1.0f/lrun[r] : 0.f;
    size_t base = ((size_t)b*2304 + s)*1280 + h*160;
    if (!ip) {
      #pragma unroll
      for (int nt=0;nt<10;nt++) hs[base + nt*16 + l16] = f2b(o[nt][r]*linv);
    } else {
      float f = mig[b*2304 + s]*scl*linv;    // mig uses TRUE b
      #pragma unroll
      for (int nt=0;nt<10;nt++)
        comb[base + nt*16 + l16] = f2b(b2f(hs[base + nt*16 + l16]) + o[nt][r]*f);
    }
  }
}

// ---------------- launch ----------------
extern "C" void kernel_launch(void* const* d_in, const int* in_sizes, int n_in,
                              void* d_out, int out_size, void* d_ws, size_t ws_size,
                              hipStream_t stream)
{
  const float* hid = (const float*)d_in[0];
  const float* Wq  = (const float*)d_in[1];
  const float* Wk  = (const float*)d_in[2];
  const float* Wv  = (const float*)d_in[3];
  const float* Wo  = (const float*)d_in[4];
  const float* bo  = (const float*)d_in[5];
  const float* sks = (const float*)d_in[6];
  const float* svs = (const float*)d_in[7];
  const void*  mid = d_in[8];
  const float* mig = (const float*)d_in[9];
  const void*  scl = d_in[10];

  char* ws = (char*)d_ws;                    // 69.9 MiB total (aliased, stream-ordered)
  float* mk   = (float*)(ws);                // [2][2304] additive offsets  18432 B
  float* mg   = (float*)(ws + 18432);        // [2][2304]              18432 B
  u16*  WT    = (u16*)(ws + 40960);          // 4 x 1280x1280 bf16  13107200 B
  u16*  slotA = (u16*)(ws + 13148160);       // hidB; later sksB [16][2304][160]  11796480
  u16*  q     = (u16*)(ws + 25534464);       // NATURAL [2][2304][1280] pre-scaled 11796480
  u16*  slotB = (u16*)(ws + 37330944);       // k NATURAL; later comb             11796480
  u16*  vt    = (u16*)(ws + 49717248);       // v^T; later vst                    11796480
  u16*  hsB   = (u16*)(ws + 61513728);       // self-attn out bf16                11796480

  maskprep <<<dim3(18),      256, 0, stream>>>(mid, mig, mk, mg);
  prep_w   <<<dim3(40,40,5), 256, 0, stream>>>(Wq, Wk, Wv, Wo, WT, hid, slotA);
  gemm128  <<<dim3(36,10,3), 256, 0, stream>>>(slotA, WT, q, slotB, vt, nullptr, nullptr, 0);
  attn     <<<dim3(36,16),   256, 0, stream>>>(q, slotB, vt, nullptr, nullptr, hsB, nullptr, scl, 0);
  prep_vs  <<<dim3(72,5,17), 256, 0, stream>>>(svs, vt, sks, slotA);               // vt dead -> vst; hidB dead -> sksB
  attn     <<<dim3(36,16),   256, 0, stream>>>(q, slotA, vt, mk, mg, hsB, slotB, scl, 1); // k dead -> comb
  gemm128  <<<dim3(36,10,1), 256, 0, stream>>>(slotB, WT + (size_t)3*1280*1280,
                                               nullptr, nullptr, nullptr, (float*)d_out, bo, 1);
}